// Round 1
// baseline (364.908 us; speedup 1.0000x reference)
//
#include <hip/hip_runtime.h>
#include <stdint.h>
#include <math.h>

// Problem constants (fixed by the reference)
#define NB    32          // graphs
#define NNODE 2048        // nodes per graph
#define NT    (NB*NNODE)  // 65536 total nodes
#define EPB   16384       // edges per graph
#define ETOT  (NB*EPB)    // 524288 edges
#define DF    128         // feature dim (DIN == H == 128)
#define KSEL  615         // ceil(0.3*2048)

// ---------------- CSR build ----------------

__global__ void k_deg(const int* __restrict__ edst, uint32_t* __restrict__ deg){
  int e = blockIdx.x*256 + threadIdx.x;          // grid exactly covers ETOT
  int g = e >> 14;                               // EPB = 2^14
  atomicAdd(&deg[g*NNODE + edst[e]], 1u);
}

__global__ __launch_bounds__(1024) void k_scan1(const uint32_t* __restrict__ deg,
                        uint32_t* __restrict__ rowptr, uint32_t* __restrict__ bsum){
  __shared__ uint32_t sh[1024];
  int t = threadIdx.x; int base = blockIdx.x*1024;
  uint32_t v = deg[base+t];
  sh[t] = v;
  for (int off=1; off<1024; off<<=1){
    __syncthreads();
    uint32_t a = (t>=off) ? sh[t-off] : 0u;
    __syncthreads();
    sh[t] += a;
  }
  rowptr[base+t] = sh[t] - v;                    // block-local exclusive scan
  if (t==1023) bsum[blockIdx.x] = sh[1023];
}

__global__ void k_scan2(uint32_t* __restrict__ bsum){
  __shared__ uint32_t sh[64];
  int t = threadIdx.x;
  uint32_t v = bsum[t]; sh[t] = v;
  for (int off=1; off<64; off<<=1){
    __syncthreads();
    uint32_t a = (t>=off) ? sh[t-off] : 0u;
    __syncthreads();
    sh[t] += a;
  }
  bsum[t] = sh[t] - v;                           // exclusive block offsets
}

__global__ __launch_bounds__(1024) void k_scan3(uint32_t* __restrict__ rowptr,
                                                const uint32_t* __restrict__ bsum){
  int i = blockIdx.x*1024 + threadIdx.x;
  rowptr[i] += bsum[i>>10];
  if (i==0) rowptr[NT] = ETOT;                   // every edge lands in range
}

// consumes deg as the per-bucket cursor (atomicSub -> slot)
__global__ void k_scatter(const int* __restrict__ esrc, const int* __restrict__ edst,
                          const uint32_t* __restrict__ rowptr, uint32_t* __restrict__ deg,
                          int* __restrict__ col){
  int e = blockIdx.x*256 + threadIdx.x;
  int g = e >> 14;
  int d = g*NNODE + edst[e];
  int s = g*NNODE + esrc[e];
  uint32_t old = atomicSub(&deg[d], 1u);
  col[rowptr[d] + old - 1u] = s;
}

// WT[k][c] = W[c][k]  (128x128, one-time; lets the GEMM stage W coalesced)
__global__ void k_transpose(const float* __restrict__ W, float* __restrict__ WT){
  int idx = blockIdx.x*256 + threadIdx.x;        // 64 blocks -> 16384
  int k = idx & 127, c = idx >> 7;
  WT[k*DF + c] = W[c*DF + k];
}

// ---------------- mean aggregation (pull via CSR) ----------------
__global__ __launch_bounds__(128) void k_agg(const float* __restrict__ X, float* __restrict__ AGG,
                      const uint32_t* __restrict__ rowptr, const int* __restrict__ col){
  int i = blockIdx.x; int t = threadIdx.x;       // one 128-thread block per node
  uint32_t b = rowptr[i], e = rowptr[i+1];
  float acc = 0.f;
  for (uint32_t k=b; k<e; ++k){
    int s = col[k];
    acc += X[(size_t)s*DF + t];                  // 512B coalesced row read
  }
  float d = (float)((e > b) ? (e - b) : 1u);
  AGG[(size_t)i*DF + t] = acc / d;
}

// ---------------- fused SAGE combine: OUT = relu(A@Wl.T + X@Wr.T + b) -------
// tile: 32 rows x 128 cols per 256-thread block; thread = 4 rows x 4 cols.
// optional epilogue: scores[row] = tanh(dot(OUT[row], pool_w)/||pool_w||)
__global__ __launch_bounds__(256) void k_comb(
    const float* __restrict__ A, const float* __restrict__ X,
    const float* __restrict__ WlT, const float* __restrict__ WrT,
    const float* __restrict__ bias, float* __restrict__ OUT,
    const float* __restrict__ pool_w, float* __restrict__ scores)
{
  __shared__ float4 AXs[2048];                   // [2][32 rows][32 float4] = 32KB
  __shared__ float4 Wts[1024];                   // [32 kk][32 float4] = 16KB
  const int tid = threadIdx.x;
  const int rowBase = blockIdx.x * 32;

  const float4* Ag = (const float4*)(A + (size_t)rowBase*DF);
  const float4* Xg = (const float4*)(X + (size_t)rowBase*DF);
  #pragma unroll
  for (int n=0; n<4; ++n){
    AXs[tid + n*256]        = Ag[tid + n*256];
    AXs[1024 + tid + n*256] = Xg[tid + n*256];
  }

  const int c4 = tid & 31;                       // float4-column 0..31
  const int r4 = tid >> 5;                       // row group 0..7 (4 rows each)
  float acc[4][4];
  #pragma unroll
  for (int j=0;j<4;++j){ acc[j][0]=0.f; acc[j][1]=0.f; acc[j][2]=0.f; acc[j][3]=0.f; }

  for (int pass=0; pass<2; ++pass){
    const float* WT = pass ? WrT : WlT;
    const float4* Asrc4 = AXs + pass*1024;
    for (int kc=0; kc<DF; kc+=32){
      __syncthreads();
      const float4* Wg = (const float4*)(WT + kc*DF);
      #pragma unroll
      for (int n=0;n<4;++n) Wts[tid + n*256] = Wg[tid + n*256];   // Wt[kk][c]
      __syncthreads();
      #pragma unroll
      for (int kk=0; kk<32; kk+=4){
        float4 w0 = Wts[(kk+0)*32 + c4];
        float4 w1 = Wts[(kk+1)*32 + c4];
        float4 w2 = Wts[(kk+2)*32 + c4];
        float4 w3 = Wts[(kk+3)*32 + c4];
        #pragma unroll
        for (int j=0;j<4;++j){
          float4 av = Asrc4[(r4*4+j)*32 + ((kc+kk)>>2)];          // broadcast
          acc[j][0] = fmaf(av.x,w0.x,fmaf(av.y,w1.x,fmaf(av.z,w2.x,fmaf(av.w,w3.x,acc[j][0]))));
          acc[j][1] = fmaf(av.x,w0.y,fmaf(av.y,w1.y,fmaf(av.z,w2.y,fmaf(av.w,w3.y,acc[j][1]))));
          acc[j][2] = fmaf(av.x,w0.z,fmaf(av.y,w1.z,fmaf(av.z,w2.z,fmaf(av.w,w3.z,acc[j][2]))));
          acc[j][3] = fmaf(av.x,w0.w,fmaf(av.y,w1.w,fmaf(av.z,w2.w,fmaf(av.w,w3.w,acc[j][3]))));
        }
      }
    }
  }

  float4 b4 = ((const float4*)bias)[c4];
  float o[4][4];
  #pragma unroll
  for (int j=0;j<4;++j){
    o[j][0] = fmaxf(acc[j][0] + b4.x, 0.f);
    o[j][1] = fmaxf(acc[j][1] + b4.y, 0.f);
    o[j][2] = fmaxf(acc[j][2] + b4.z, 0.f);
    o[j][3] = fmaxf(acc[j][3] + b4.w, 0.f);
    float4 ov; ov.x=o[j][0]; ov.y=o[j][1]; ov.z=o[j][2]; ov.w=o[j][3];
    ((float4*)(OUT + (size_t)(rowBase + r4*4 + j)*DF))[c4] = ov;
  }

  if (scores){
    float4 pw4 = ((const float4*)pool_w)[c4];
    float n2 = pw4.x*pw4.x + pw4.y*pw4.y + pw4.z*pw4.z + pw4.w*pw4.w;
    #pragma unroll
    for (int m=16; m>=1; m>>=1) n2 += __shfl_xor(n2, m, 64);      // 32-lane row group
    float nrm = sqrtf(n2);
    #pragma unroll
    for (int j=0;j<4;++j){
      float p = o[j][0]*pw4.x + o[j][1]*pw4.y + o[j][2]*pw4.z + o[j][3]*pw4.w;
      #pragma unroll
      for (int m=16; m>=1; m>>=1) p += __shfl_xor(p, m, 64);
      if (c4 == 0) scores[rowBase + r4*4 + j] = tanhf(p / nrm);
    }
  }
}

// ---------------- top-k (exact, jax tie-break) + pool + classifier ----------
__global__ __launch_bounds__(1024) void k_topk(
    const float* __restrict__ scores, const float* __restrict__ H,
    const float* __restrict__ Wc1, const float* __restrict__ bc1,
    const float* __restrict__ Wc2, const float* __restrict__ bc2,
    float* __restrict__ out)
{
  __shared__ uint64_t keys[NNODE];               // 16KB
  __shared__ float part[8*DF];
  __shared__ float emb[DF];
  __shared__ float hred[DF];
  const int t = threadIdx.x; const int b = blockIdx.x;
  const float* sc = scores + b*NNODE;

  // key = (~monotone(score) << 32) | idx  -> ascending sort == desc score, asc idx
  for (int i=t; i<NNODE; i+=1024){
    uint32_t u = __float_as_uint(sc[i]);
    uint32_t m = (u & 0x80000000u) ? ~u : (u | 0x80000000u);
    keys[i] = ((uint64_t)(~m) << 32) | (uint32_t)i;
  }
  __syncthreads();

  for (int k=2; k<=NNODE; k<<=1){
    for (int j=k>>1; j>0; j>>=1){
      int i = ((t & ~(j-1)) << 1) | (t & (j-1));
      int p = i | j;
      uint64_t a = keys[i], c = keys[p];
      bool up = ((i & k) == 0);
      if ((a > c) == up){ keys[i] = c; keys[p] = a; }
      __syncthreads();
    }
  }

  // gated mean over the 615 selected nodes
  const int pg = t >> 7, f = t & (DF-1);
  float accv = 0.f;
  for (int s2=pg; s2<KSEL; s2+=8){
    uint64_t kv = keys[s2];
    uint32_t idx = (uint32_t)kv;                 // local node id
    uint32_t m = ~(uint32_t)(kv >> 32);          // decode score
    uint32_t u = (m & 0x80000000u) ? (m ^ 0x80000000u) : ~m;
    float val = __uint_as_float(u);
    accv += val * H[((size_t)b*NNODE + idx)*DF + f];
  }
  part[pg*DF + f] = accv;
  __syncthreads();
  if (t < DF){
    float e = 0.f;
    for (int g2=0; g2<8; ++g2) e += part[g2*DF + t];
    emb[t] = e / (float)KSEL;
  }
  __syncthreads();
  if (t < DF){
    float hv = bc1[t];
    const float* wr = Wc1 + t*DF;
    for (int f2=0; f2<DF; ++f2) hv = fmaf(emb[f2], wr[f2], hv);
    hred[t] = fmaxf(hv, 0.f) * Wc2[t];
  }
  __syncthreads();
  if (t == 0){
    float o = bc2[0];
    for (int c2=0; c2<DF; ++c2) o += hred[c2];
    out[b] = o;
  }
}

// ---------------- launch ----------------
extern "C" void kernel_launch(void* const* d_in, const int* in_sizes, int n_in,
                              void* d_out, int out_size, void* d_ws, size_t ws_size,
                              hipStream_t stream)
{
  (void)in_sizes; (void)n_in; (void)out_size; (void)ws_size;
  const float* x   = (const float*)d_in[0];
  const int* esrc  = (const int*)d_in[1];
  const int* edst  = (const int*)d_in[2];
  const float* Wl1 = (const float*)d_in[3];
  const float* bl1 = (const float*)d_in[4];
  const float* Wr1 = (const float*)d_in[5];
  const float* Wl2 = (const float*)d_in[6];
  const float* bl2 = (const float*)d_in[7];
  const float* Wr2 = (const float*)d_in[8];
  const float* pw  = (const float*)d_in[9];
  const float* Wc1 = (const float*)d_in[10];
  const float* bc1 = (const float*)d_in[11];
  const float* Wc2 = (const float*)d_in[12];
  const float* bc2 = (const float*)d_in[13];
  float* out = (float*)d_out;

  char* ws = (char*)d_ws;
  float*    buf0   = (float*)   (ws + 0);          // 32MB: AGG1 -> AGG2 -> H2
  float*    buf1   = (float*)   (ws + 33554432);   // 32MB: H1
  uint32_t* deg    = (uint32_t*)(ws + 67108864);   // 256KB (also scatter cursor)
  uint32_t* rowptr = (uint32_t*)(ws + 67371008);   // 65537 u32
  int*      col    = (int*)     (ws + 67633408);   // 2MB
  float*    scores = (float*)   (ws + 69730560);   // 256KB
  uint32_t* bsum   = (uint32_t*)(ws + 69992704);   // 256B
  float*    wts    = (float*)   (ws + 69992960);   // 4 x 64KB transposed weights
  float* WlT1 = wts;          float* WrT1 = wts + 16384;
  float* WlT2 = wts + 32768;  float* WrT2 = wts + 49152;

  hipMemsetAsync(deg, 0, NT*sizeof(uint32_t), stream);

  k_deg    <<<ETOT/256, 256, 0, stream>>>(edst, deg);
  k_scan1  <<<64, 1024, 0, stream>>>(deg, rowptr, bsum);
  k_scan2  <<<1, 64, 0, stream>>>(bsum);
  k_scan3  <<<64, 1024, 0, stream>>>(rowptr, bsum);
  k_scatter<<<ETOT/256, 256, 0, stream>>>(esrc, edst, rowptr, deg, col);

  k_transpose<<<64, 256, 0, stream>>>(Wl1, WlT1);
  k_transpose<<<64, 256, 0, stream>>>(Wr1, WrT1);
  k_transpose<<<64, 256, 0, stream>>>(Wl2, WlT2);
  k_transpose<<<64, 256, 0, stream>>>(Wr2, WrT2);

  // layer 1
  k_agg <<<NT, 128, 0, stream>>>(x, buf0, rowptr, col);
  k_comb<<<NT/32, 256, 0, stream>>>(buf0, x, WlT1, WrT1, bl1, buf1, nullptr, nullptr);
  // layer 2 (H2 overwrites buf0 in place; rows are block-private) + fused scores
  k_agg <<<NT, 128, 0, stream>>>(buf1, buf0, rowptr, col);
  k_comb<<<NT/32, 256, 0, stream>>>(buf0, buf1, WlT2, WrT2, bl2, buf0, pw, scores);

  // top-k + gated mean pool + MLP classifier
  k_topk<<<NB, 1024, 0, stream>>>(scores, buf0, Wc1, bc1, Wc2, bc2, out);
}

// Round 2
// 260.439 us; speedup vs baseline: 1.4011x; 1.4011x over previous
//
#include <hip/hip_runtime.h>
#include <stdint.h>
#include <math.h>

// Problem constants (fixed by the reference)
#define NB    32          // graphs
#define NNODE 2048        // nodes per graph
#define NT    (NB*NNODE)  // 65536 total nodes
#define EPB   16384       // edges per graph
#define ETOT  (NB*EPB)    // 524288 edges
#define DF    128         // feature dim
#define KSEL  615         // ceil(0.3*2048)

typedef __attribute__((ext_vector_type(8))) short bf16x8;
typedef __attribute__((ext_vector_type(4))) float f32x4;

// ---- split-precision helpers: f32 ~= hi(bf16) + lo(bf16), err ~2^-17 ----
__device__ __forceinline__ unsigned short f2bf(float f){
  uint32_t u = __float_as_uint(f);
  u += 0x7FFFu + ((u>>16)&1u);                 // RNE
  return (unsigned short)(u>>16);
}
__device__ __forceinline__ void split2(float f, unsigned short& hi, unsigned short& lo){
  unsigned short h = f2bf(f);
  float fh = __uint_as_float(((uint32_t)h)<<16);
  hi = h;
  lo = f2bf(f - fh);
}
__device__ __forceinline__ float bf2f(unsigned short u){
  return __uint_as_float(((uint32_t)u)<<16);
}

// Packed operand layout (per row, 1KB): 8 k-steps of 32; per k-step 64 elems:
// [hi bf16 x32][lo bf16 x32].  ks 0..3 = AGG features (k 0..127, Wl half),
// ks 4..7 = X features (k 128..255, Wr half).

// ---------------- CSR build ----------------
__global__ void k_deg(const int* __restrict__ edst, uint32_t* __restrict__ deg){
  int e = blockIdx.x*256 + threadIdx.x;
  int g = e >> 14;
  atomicAdd(&deg[g*NNODE + edst[e]], 1u);
}

__global__ __launch_bounds__(1024) void k_scan1(const uint32_t* __restrict__ deg,
                        uint32_t* __restrict__ rowptr, uint32_t* __restrict__ bsum){
  __shared__ uint32_t sh[1024];
  int t = threadIdx.x; int base = blockIdx.x*1024;
  uint32_t v = deg[base+t];
  sh[t] = v;
  for (int off=1; off<1024; off<<=1){
    __syncthreads();
    uint32_t a = (t>=off) ? sh[t-off] : 0u;
    __syncthreads();
    sh[t] += a;
  }
  rowptr[base+t] = sh[t] - v;
  if (t==1023) bsum[blockIdx.x] = sh[1023];
}

__global__ void k_scan2(uint32_t* __restrict__ bsum){
  __shared__ uint32_t sh[64];
  int t = threadIdx.x;
  uint32_t v = bsum[t]; sh[t] = v;
  for (int off=1; off<64; off<<=1){
    __syncthreads();
    uint32_t a = (t>=off) ? sh[t-off] : 0u;
    __syncthreads();
    sh[t] += a;
  }
  bsum[t] = sh[t] - v;
}

__global__ __launch_bounds__(1024) void k_scan3(uint32_t* __restrict__ rowptr,
                                                const uint32_t* __restrict__ bsum){
  int i = blockIdx.x*1024 + threadIdx.x;
  rowptr[i] += bsum[i>>10];
  if (i==0) rowptr[NT] = ETOT;
}

__global__ void k_scatter(const int* __restrict__ esrc, const int* __restrict__ edst,
                          const uint32_t* __restrict__ rowptr, uint32_t* __restrict__ deg,
                          int* __restrict__ col){
  int e = blockIdx.x*256 + threadIdx.x;
  int g = e >> 14;
  int d = g*NNODE + edst[e];
  int s = g*NNODE + esrc[e];
  uint32_t old = atomicSub(&deg[d], 1u);
  col[rowptr[d] + old - 1u] = s;
}

// ---------------- weight pack: B[k][c] (k<128:Wl, else Wr) -> MFMA frags ----
// Bpk elem offset = (((ks*8+ct)*2+part)*64 + lane)*8 ; per layer 65536 elems.
__global__ void k_packB(const float* __restrict__ Wl, const float* __restrict__ Wr,
                        unsigned short* __restrict__ Bpk){
  int t = blockIdx.x*256 + threadIdx.x;        // 4096 threads per layer
  int lane = t & 63;
  int ct   = (t>>6) & 7;
  int ks   = (t>>9) & 7;
  int c  = ct*16 + (lane & 15);
  int k0 = ks*32 + ((lane>>4)<<3);
  size_t base = ((size_t)((ks*8+ct)*2)*64 + lane)*8;
  #pragma unroll
  for (int j=0;j<8;++j){
    int k = k0 + j;
    float v = (k < DF) ? Wl[c*DF + k] : Wr[c*DF + (k-DF)];
    unsigned short h, l; split2(v, h, l);
    Bpk[base + j]       = h;
    Bpk[base + 512 + j] = l;                   // part=1 stride = 64*8
  }
}

// ---------------- pack x (f32 row-major) into APK x-region -----------------
__global__ void k_pack(const float* __restrict__ X, unsigned short* __restrict__ APK){
  int t = blockIdx.x*256 + threadIdx.x;        // NT*16 threads, 8 feats each
  int row = t >> 4, seg = t & 15;
  const float4* X4 = (const float4*)X;
  float4 a = X4[row*32 + seg*2];
  float4 b = X4[row*32 + seg*2 + 1];
  float v[8] = {a.x,a.y,a.z,a.w,b.x,b.y,b.z,b.w};
  bf16x8 hv, lv;
  #pragma unroll
  for (int j=0;j<8;++j){
    unsigned short h, l; split2(v[j], h, l);
    hv[j] = (short)h; lv[j] = (short)l;
  }
  int ks = seg>>2, q = seg&3;
  unsigned short* dst = APK + (size_t)row*512 + (4+ks)*64 + q*8;
  *(bf16x8*)dst = hv;
  *(bf16x8*)(dst+32) = lv;
}

// ---------------- mean aggregation -> packed agg region --------------------
// one wave per node; lane = (f4 group c, half h); halves interleave edges.
template<int LAYER>
__global__ __launch_bounds__(256) void k_agg(const float* __restrict__ X,
      unsigned short* __restrict__ APK, const uint32_t* __restrict__ rowptr,
      const int* __restrict__ col){
  int i = blockIdx.x*4 + (threadIdx.x>>6);
  int l = threadIdx.x & 63, c = l & 31, h = l >> 5;
  uint32_t b = rowptr[i], e = rowptr[i+1];
  float ax=0.f, ay=0.f, az=0.f, aw=0.f;
  if constexpr (LAYER==1){
    const float4* X4 = (const float4*)X;
    for (uint32_t k=b+h; k<e; k+=2){
      int s = col[k];
      float4 v = X4[(size_t)s*32 + c];
      ax+=v.x; ay+=v.y; az+=v.z; aw+=v.w;
    }
  } else {
    for (uint32_t k=b+h; k<e; k+=2){
      int s = col[k];
      const unsigned short* p = APK + (size_t)s*512 + 256 + (c>>3)*64 + 4*(c&7);
      ushort4 hv = *(const ushort4*)p;
      ushort4 lv = *(const ushort4*)(p+32);
      ax += bf2f(hv.x)+bf2f(lv.x);
      ay += bf2f(hv.y)+bf2f(lv.y);
      az += bf2f(hv.z)+bf2f(lv.z);
      aw += bf2f(hv.w)+bf2f(lv.w);
    }
  }
  ax += __shfl_xor(ax,32,64); ay += __shfl_xor(ay,32,64);
  az += __shfl_xor(az,32,64); aw += __shfl_xor(aw,32,64);
  if (h==0){
    float invd = 1.0f / (float)((e>b)?(e-b):1u);
    unsigned short h0,l0,h1,l1,h2,l2,h3,l3;
    split2(ax*invd,h0,l0); split2(ay*invd,h1,l1);
    split2(az*invd,h2,l2); split2(aw*invd,h3,l3);
    unsigned short* dst = APK + (size_t)i*512 + (c>>3)*64 + 4*(c&7);
    *(ushort4*)dst      = make_ushort4(h0,h1,h2,h3);
    *(ushort4*)(dst+32) = make_ushort4(l0,l1,l2,l3);
  }
}

// ---------------- fused SAGE combine via split-bf16 MFMA -------------------
// wave: 16 rows x 128 cols (8 ct tiles of 16x16), K=256 in 8 steps of 32.
// 3 MFMAs per (ct,ks): hi*hi + hi*lo + lo*hi.
template<int LAYER>
__global__ __launch_bounds__(256) void k_comb(
    const unsigned short* __restrict__ APKc, unsigned short* __restrict__ APKw,
    const unsigned short* __restrict__ Bpk, const float* __restrict__ bias,
    float* __restrict__ OUT, const float* __restrict__ pw,
    float* __restrict__ scores)
{
  int l = threadIdx.x & 63, w = threadIdx.x >> 6;
  int rowBase = blockIdx.x*64 + w*16;
  int q = l >> 4, c16 = l & 15;
  int arow = rowBase + c16;

  f32x4 acc[8];
  #pragma unroll
  for (int ct=0; ct<8; ++ct) acc[ct] = (f32x4){0.f,0.f,0.f,0.f};

  const unsigned short* ap = APKc + (size_t)arow*512 + q*8;
  #pragma unroll 2
  for (int ks=0; ks<8; ++ks){
    bf16x8 ahi = *(const bf16x8*)(ap + ks*64);
    bf16x8 alo = *(const bf16x8*)(ap + ks*64 + 32);
    const unsigned short* bp = Bpk + (size_t)ks*8192 + l*8;
    #pragma unroll
    for (int ct=0; ct<8; ++ct){
      bf16x8 bhi = *(const bf16x8*)(bp + ct*1024);
      bf16x8 blo = *(const bf16x8*)(bp + ct*1024 + 512);
      acc[ct] = __builtin_amdgcn_mfma_f32_16x16x32_bf16(ahi, bhi, acc[ct], 0,0,0);
      acc[ct] = __builtin_amdgcn_mfma_f32_16x16x32_bf16(ahi, blo, acc[ct], 0,0,0);
      acc[ct] = __builtin_amdgcn_mfma_f32_16x16x32_bf16(alo, bhi, acc[ct], 0,0,0);
    }
  }

  // layer1 overwrites the x-region of rows this block just read -> drain first
  __syncthreads();

  if constexpr (LAYER==1){
    #pragma unroll
    for (int ct=0; ct<8; ++ct){
      int c = ct*16 + c16;
      float bv = bias[c];
      #pragma unroll
      for (int r=0; r<4; ++r){
        int grow = rowBase + q*4 + r;
        float o = fmaxf(acc[ct][r] + bv, 0.f);
        unsigned short hh, ll; split2(o, hh, ll);
        unsigned short* d2 = APKw + (size_t)grow*512 + 256 + (c>>5)*64 + (c&31);
        d2[0]  = hh;
        d2[32] = ll;
      }
    }
  } else {
    float ov[8][4];
    float pwv[8];
    float n2 = 0.f;
    #pragma unroll
    for (int ct=0; ct<8; ++ct){ pwv[ct] = pw[ct*16 + c16]; n2 += pwv[ct]*pwv[ct]; }
    n2 += __shfl_xor(n2,8,16); n2 += __shfl_xor(n2,4,16);
    n2 += __shfl_xor(n2,2,16); n2 += __shfl_xor(n2,1,16);
    float nrm = sqrtf(n2);
    #pragma unroll
    for (int ct=0; ct<8; ++ct){
      int c = ct*16 + c16;
      float bv = bias[c];
      #pragma unroll
      for (int r=0; r<4; ++r){
        int grow = rowBase + q*4 + r;
        float o = fmaxf(acc[ct][r] + bv, 0.f);
        OUT[(size_t)grow*DF + c] = o;
        ov[ct][r] = o;
      }
    }
    #pragma unroll
    for (int r=0; r<4; ++r){
      float p = 0.f;
      #pragma unroll
      for (int ct=0; ct<8; ++ct) p += ov[ct][r]*pwv[ct];
      p += __shfl_xor(p,8,16); p += __shfl_xor(p,4,16);
      p += __shfl_xor(p,2,16); p += __shfl_xor(p,1,16);
      if (c16 == 0) scores[rowBase + q*4 + r] = tanhf(p/nrm);
    }
  }
}

// ---------------- top-k (exact, jax tie-break) + pool + classifier ---------
__global__ __launch_bounds__(1024) void k_topk(
    const float* __restrict__ scores, const float* __restrict__ H,
    const float* __restrict__ Wc1, const float* __restrict__ bc1,
    const float* __restrict__ Wc2, const float* __restrict__ bc2,
    float* __restrict__ out)
{
  __shared__ uint64_t keys[NNODE];
  __shared__ float part[8*DF];
  __shared__ float emb[DF];
  __shared__ float hred[DF];
  const int t = threadIdx.x; const int b = blockIdx.x;
  const float* sc = scores + b*NNODE;

  for (int i=t; i<NNODE; i+=1024){
    uint32_t u = __float_as_uint(sc[i]);
    uint32_t m = (u & 0x80000000u) ? ~u : (u | 0x80000000u);
    keys[i] = ((uint64_t)(~m) << 32) | (uint32_t)i;
  }
  __syncthreads();

  for (int k=2; k<=NNODE; k<<=1){
    for (int j=k>>1; j>0; j>>=1){
      int i = ((t & ~(j-1)) << 1) | (t & (j-1));
      int p = i | j;
      uint64_t a = keys[i], c = keys[p];
      bool up = ((i & k) == 0);
      if ((a > c) == up){ keys[i] = c; keys[p] = a; }
      __syncthreads();
    }
  }

  const int pg = t >> 7, f = t & (DF-1);
  float accv = 0.f;
  for (int s2=pg; s2<KSEL; s2+=8){
    uint64_t kv = keys[s2];
    uint32_t idx = (uint32_t)kv;
    uint32_t m = ~(uint32_t)(kv >> 32);
    uint32_t u = (m & 0x80000000u) ? (m ^ 0x80000000u) : ~m;
    float val = __uint_as_float(u);
    accv += val * H[((size_t)b*NNODE + idx)*DF + f];
  }
  part[pg*DF + f] = accv;
  __syncthreads();
  if (t < DF){
    float e = 0.f;
    for (int g2=0; g2<8; ++g2) e += part[g2*DF + t];
    emb[t] = e / (float)KSEL;
  }
  __syncthreads();
  if (t < DF){
    float hv = bc1[t];
    const float* wr = Wc1 + t*DF;
    for (int f2=0; f2<DF; ++f2) hv = fmaf(emb[f2], wr[f2], hv);
    hred[t] = fmaxf(hv, 0.f) * Wc2[t];
  }
  __syncthreads();
  if (t == 0){
    float o = bc2[0];
    for (int c2=0; c2<DF; ++c2) o += hred[c2];
    out[b] = o;
  }
}

// ---------------- launch ----------------
extern "C" void kernel_launch(void* const* d_in, const int* in_sizes, int n_in,
                              void* d_out, int out_size, void* d_ws, size_t ws_size,
                              hipStream_t stream)
{
  (void)in_sizes; (void)n_in; (void)out_size; (void)ws_size;
  const float* x   = (const float*)d_in[0];
  const int* esrc  = (const int*)d_in[1];
  const int* edst  = (const int*)d_in[2];
  const float* Wl1 = (const float*)d_in[3];
  const float* bl1 = (const float*)d_in[4];
  const float* Wr1 = (const float*)d_in[5];
  const float* Wl2 = (const float*)d_in[6];
  const float* bl2 = (const float*)d_in[7];
  const float* Wr2 = (const float*)d_in[8];
  const float* pw  = (const float*)d_in[9];
  const float* Wc1 = (const float*)d_in[10];
  const float* bc1 = (const float*)d_in[11];
  const float* Wc2 = (const float*)d_in[12];
  const float* bc2 = (const float*)d_in[13];
  float* out = (float*)d_out;

  char* ws = (char*)d_ws;                       // ~99 MB used
  unsigned short* APK = (unsigned short*)(ws);  // 64MB packed operands
  float*    H2     = (float*)   (ws + 67108864);   // 32MB
  uint32_t* deg    = (uint32_t*)(ws + 100663296);  // 256KB
  uint32_t* rowptr = (uint32_t*)(ws + 100925440);  // 65537 u32
  int*      col    = (int*)     (ws + 101187840);  // 2MB
  float*    scores = (float*)   (ws + 103284992);  // 256KB
  uint32_t* bsum   = (uint32_t*)(ws + 103547136);  // 256B
  unsigned short* Bpk = (unsigned short*)(ws + 103547392); // 256KB (2 layers)

  hipMemsetAsync(deg, 0, NT*sizeof(uint32_t), stream);

  k_deg    <<<ETOT/256, 256, 0, stream>>>(edst, deg);
  k_scan1  <<<64, 1024, 0, stream>>>(deg, rowptr, bsum);
  k_scan2  <<<1, 64, 0, stream>>>(bsum);
  k_scan3  <<<64, 1024, 0, stream>>>(rowptr, bsum);
  k_scatter<<<ETOT/256, 256, 0, stream>>>(esrc, edst, rowptr, deg, col);

  k_packB<<<16, 256, 0, stream>>>(Wl1, Wr1, Bpk);
  k_packB<<<16, 256, 0, stream>>>(Wl2, Wr2, Bpk + 65536);
  k_pack <<<NT*16/256, 256, 0, stream>>>(x, APK);

  // layer 1: agg(x) -> APK[agg]; comb reads APK, writes H1 packed -> APK[x]
  k_agg<1> <<<NT/4, 256, 0, stream>>>(x, APK, rowptr, col);
  k_comb<1><<<NT/64, 256, 0, stream>>>(APK, APK, Bpk, bl1,
                                       nullptr, nullptr, nullptr);
  // layer 2: agg(H1 packed) -> APK[agg]; comb writes H2 f32 + scores
  k_agg<2> <<<NT/4, 256, 0, stream>>>(nullptr, APK, rowptr, col);
  k_comb<2><<<NT/64, 256, 0, stream>>>(APK, nullptr, Bpk + 65536, bl2,
                                       H2, pw, scores);

  k_topk<<<NB, 1024, 0, stream>>>(scores, H2, Wc1, bc1, Wc2, bc2, out);
}

// Round 3
// 226.169 us; speedup vs baseline: 1.6134x; 1.1515x over previous
//
#include <hip/hip_runtime.h>
#include <stdint.h>
#include <math.h>

// Problem constants (fixed by the reference)
#define NB    32          // graphs
#define NNODE 2048        // nodes per graph
#define NT    (NB*NNODE)  // 65536 total nodes
#define EPB   16384       // edges per graph
#define ETOT  (NB*EPB)    // 524288 edges
#define DF    128         // feature dim
#define KSEL  615         // ceil(0.3*2048)

typedef __attribute__((ext_vector_type(8))) short bf16x8;
typedef __attribute__((ext_vector_type(4))) float f32x4;

// ---- split-precision helpers: f32 ~= hi(bf16) + lo(bf16), err ~2^-17 ----
__device__ __forceinline__ unsigned short f2bf(float f){
  uint32_t u = __float_as_uint(f);
  u += 0x7FFFu + ((u>>16)&1u);                 // RNE
  return (unsigned short)(u>>16);
}
__device__ __forceinline__ void split2(float f, unsigned short& hi, unsigned short& lo){
  unsigned short h = f2bf(f);
  float fh = __uint_as_float(((uint32_t)h)<<16);
  hi = h;
  lo = f2bf(f - fh);
}
__device__ __forceinline__ float bf2f(unsigned short u){
  return __uint_as_float(((uint32_t)u)<<16);
}

// Packed operand layout (per row, 1KB = 512 ushorts): 8 k-steps of 32 feats;
// per k-step 64 shorts: [hi bf16 x32][lo bf16 x32].
// ks 0..3 = AGG features (k 0..127, Wl half), ks 4..7 = X features (Wr half).

// ---------------- CSR build ----------------
__global__ void k_deg(const int* __restrict__ edst, uint32_t* __restrict__ deg){
  int e = blockIdx.x*256 + threadIdx.x;
  int g = e >> 14;
  atomicAdd(&deg[g*NNODE + edst[e]], 1u);
}

__global__ __launch_bounds__(1024) void k_scan1(const uint32_t* __restrict__ deg,
                        uint32_t* __restrict__ rowptr, uint32_t* __restrict__ bsum){
  __shared__ uint32_t sh[1024];
  int t = threadIdx.x; int base = blockIdx.x*1024;
  uint32_t v = deg[base+t];
  sh[t] = v;
  for (int off=1; off<1024; off<<=1){
    __syncthreads();
    uint32_t a = (t>=off) ? sh[t-off] : 0u;
    __syncthreads();
    sh[t] += a;
  }
  rowptr[base+t] = sh[t] - v;
  if (t==1023) bsum[blockIdx.x] = sh[1023];
}

__global__ void k_scan2(uint32_t* __restrict__ bsum){
  __shared__ uint32_t sh[64];
  int t = threadIdx.x;
  uint32_t v = bsum[t]; sh[t] = v;
  for (int off=1; off<64; off<<=1){
    __syncthreads();
    uint32_t a = (t>=off) ? sh[t-off] : 0u;
    __syncthreads();
    sh[t] += a;
  }
  bsum[t] = sh[t] - v;
}

__global__ __launch_bounds__(1024) void k_scan3(uint32_t* __restrict__ rowptr,
                                                const uint32_t* __restrict__ bsum){
  int i = blockIdx.x*1024 + threadIdx.x;
  rowptr[i] += bsum[i>>10];
  if (i==0) rowptr[NT] = ETOT;
}

__global__ void k_scatter(const int* __restrict__ esrc, const int* __restrict__ edst,
                          const uint32_t* __restrict__ rowptr, uint32_t* __restrict__ deg,
                          int* __restrict__ col){
  int e = blockIdx.x*256 + threadIdx.x;
  int g = e >> 14;
  int d = g*NNODE + edst[e];
  int s = g*NNODE + esrc[e];
  uint32_t old = atomicSub(&deg[d], 1u);
  col[rowptr[d] + old - 1u] = s;
}

// ---------------- weight pack: B[k][c] (k<128:Wl, else Wr) -> MFMA frags ----
__global__ void k_packB(const float* __restrict__ Wl, const float* __restrict__ Wr,
                        unsigned short* __restrict__ Bpk){
  int t = blockIdx.x*256 + threadIdx.x;        // 4096 threads per layer
  int lane = t & 63;
  int ct   = (t>>6) & 7;
  int ks   = (t>>9) & 7;
  int c  = ct*16 + (lane & 15);
  int k0 = ks*32 + ((lane>>4)<<3);
  size_t base = ((size_t)((ks*8+ct)*2)*64 + lane)*8;
  #pragma unroll
  for (int j=0;j<8;++j){
    int k = k0 + j;
    float v = (k < DF) ? Wl[c*DF + k] : Wr[c*DF + (k-DF)];
    unsigned short h, l; split2(v, h, l);
    Bpk[base + j]       = h;
    Bpk[base + 512 + j] = l;                   // part=1 stride = 64*8
  }
}

// ---------------- mean aggregation -> packed agg region --------------------
// 32-lane group per node (lane c owns float4 = feats 4c..4c+3); 8 nodes/block.
// XCD swizzle: graph g = bid&31 -> dispatch ids = g (mod 32) -> XCD g%8.
// Layer 1 additionally packs the node's own x row (replaces k_pack).
template<int LAYER>
__global__ __launch_bounds__(256) void k_agg(const float* __restrict__ X,
      unsigned short* __restrict__ APK, const uint32_t* __restrict__ rowptr,
      const int* __restrict__ col){
  const int grp = threadIdx.x >> 5, c = threadIdx.x & 31;
  const int bid = blockIdx.x;
  const int g = bid & 31, jj = bid >> 5;          // 256 blocks per graph
  const int i = g*NNODE + jj*8 + grp;
  uint32_t b = rowptr[i], e = rowptr[i+1];
  float ax=0.f, ay=0.f, az=0.f, aw=0.f;

  if constexpr (LAYER==1){
    const float4* X4 = (const float4*)X;
    uint32_t k = b;
    for (; k+4<=e; k+=4){
      int s0=col[k], s1=col[k+1], s2=col[k+2], s3=col[k+3];
      float4 v0=X4[(size_t)s0*32+c], v1=X4[(size_t)s1*32+c],
             v2=X4[(size_t)s2*32+c], v3=X4[(size_t)s3*32+c];
      ax+=v0.x+v1.x+v2.x+v3.x; ay+=v0.y+v1.y+v2.y+v3.y;
      az+=v0.z+v1.z+v2.z+v3.z; aw+=v0.w+v1.w+v2.w+v3.w;
    }
    for (; k<e; ++k){
      float4 v = X4[(size_t)col[k]*32+c];
      ax+=v.x; ay+=v.y; az+=v.z; aw+=v.w;
    }
    // fused: pack own row's x into the x-region (row is L2-hot on this XCD)
    float4 xv = X4[(size_t)i*32 + c];
    unsigned short h0,l0,h1,l1,h2,l2,h3,l3;
    split2(xv.x,h0,l0); split2(xv.y,h1,l1);
    split2(xv.z,h2,l2); split2(xv.w,h3,l3);
    unsigned short* dx = APK + (size_t)i*512 + 256 + (c>>3)*64 + 4*(c&7);
    *(ushort4*)dx      = make_ushort4(h0,h1,h2,h3);
    *(ushort4*)(dx+32) = make_ushort4(l0,l1,l2,l3);
  } else {
    uint32_t k = b;
    const size_t off = 256 + (c>>3)*64 + 4*(c&7);
    for (; k+4<=e; k+=4){
      int s0=col[k], s1=col[k+1], s2=col[k+2], s3=col[k+3];
      const unsigned short* p0 = APK + (size_t)s0*512 + off;
      const unsigned short* p1 = APK + (size_t)s1*512 + off;
      const unsigned short* p2 = APK + (size_t)s2*512 + off;
      const unsigned short* p3 = APK + (size_t)s3*512 + off;
      ushort4 h0=*(const ushort4*)p0, L0=*(const ushort4*)(p0+32);
      ushort4 h1=*(const ushort4*)p1, L1=*(const ushort4*)(p1+32);
      ushort4 h2=*(const ushort4*)p2, L2=*(const ushort4*)(p2+32);
      ushort4 h3=*(const ushort4*)p3, L3=*(const ushort4*)(p3+32);
      ax += bf2f(h0.x)+bf2f(L0.x)+bf2f(h1.x)+bf2f(L1.x)+bf2f(h2.x)+bf2f(L2.x)+bf2f(h3.x)+bf2f(L3.x);
      ay += bf2f(h0.y)+bf2f(L0.y)+bf2f(h1.y)+bf2f(L1.y)+bf2f(h2.y)+bf2f(L2.y)+bf2f(h3.y)+bf2f(L3.y);
      az += bf2f(h0.z)+bf2f(L0.z)+bf2f(h1.z)+bf2f(L1.z)+bf2f(h2.z)+bf2f(L2.z)+bf2f(h3.z)+bf2f(L3.z);
      aw += bf2f(h0.w)+bf2f(L0.w)+bf2f(h1.w)+bf2f(L1.w)+bf2f(h2.w)+bf2f(L2.w)+bf2f(h3.w)+bf2f(L3.w);
    }
    for (; k<e; ++k){
      const unsigned short* p = APK + (size_t)col[k]*512 + off;
      ushort4 hv=*(const ushort4*)p, lv=*(const ushort4*)(p+32);
      ax += bf2f(hv.x)+bf2f(lv.x);
      ay += bf2f(hv.y)+bf2f(lv.y);
      az += bf2f(hv.z)+bf2f(lv.z);
      aw += bf2f(hv.w)+bf2f(lv.w);
    }
  }

  float invd = 1.0f / (float)((e>b)?(e-b):1u);
  unsigned short h0,l0,h1,l1,h2,l2,h3,l3;
  split2(ax*invd,h0,l0); split2(ay*invd,h1,l1);
  split2(az*invd,h2,l2); split2(aw*invd,h3,l3);
  unsigned short* dst = APK + (size_t)i*512 + (c>>3)*64 + 4*(c&7);
  *(ushort4*)dst      = make_ushort4(h0,h1,h2,h3);
  *(ushort4*)(dst+32) = make_ushort4(l0,l1,l2,l3);
}

// ---------------- fused SAGE combine via split-bf16 MFMA -------------------
// wave: 16 rows x 128 cols (8 ct tiles of 16x16), K=256 in 8 steps of 32.
// 3 MFMAs per (ct,ks): hi*hi + hi*lo + lo*hi.  XCD-swizzled like k_agg.
template<int LAYER>
__global__ __launch_bounds__(256) void k_comb(
    const unsigned short* __restrict__ APKc, unsigned short* __restrict__ APKw,
    const unsigned short* __restrict__ Bpk, const float* __restrict__ bias,
    float* __restrict__ OUT, const float* __restrict__ pw,
    float* __restrict__ scores)
{
  int l = threadIdx.x & 63, w = threadIdx.x >> 6;
  int g = blockIdx.x & 31, jb = blockIdx.x >> 5;   // 32 blocks per graph
  int rowBase = g*NNODE + jb*64 + w*16;
  int q = l >> 4, c16 = l & 15;
  int arow = rowBase + c16;

  f32x4 acc[8];
  #pragma unroll
  for (int ct=0; ct<8; ++ct) acc[ct] = (f32x4){0.f,0.f,0.f,0.f};

  const unsigned short* ap = APKc + (size_t)arow*512 + q*8;
  #pragma unroll 2
  for (int ks=0; ks<8; ++ks){
    bf16x8 ahi = *(const bf16x8*)(ap + ks*64);
    bf16x8 alo = *(const bf16x8*)(ap + ks*64 + 32);
    const unsigned short* bp = Bpk + (size_t)ks*8192 + l*8;
    #pragma unroll
    for (int ct=0; ct<8; ++ct){
      bf16x8 bhi = *(const bf16x8*)(bp + ct*1024);
      bf16x8 blo = *(const bf16x8*)(bp + ct*1024 + 512);
      acc[ct] = __builtin_amdgcn_mfma_f32_16x16x32_bf16(ahi, bhi, acc[ct], 0,0,0);
      acc[ct] = __builtin_amdgcn_mfma_f32_16x16x32_bf16(ahi, blo, acc[ct], 0,0,0);
      acc[ct] = __builtin_amdgcn_mfma_f32_16x16x32_bf16(alo, bhi, acc[ct], 0,0,0);
    }
  }

  __syncthreads();

  if constexpr (LAYER==1){
    #pragma unroll
    for (int ct=0; ct<8; ++ct){
      int c = ct*16 + c16;
      float bv = bias[c];
      #pragma unroll
      for (int r=0; r<4; ++r){
        int grow = rowBase + q*4 + r;
        float o = fmaxf(acc[ct][r] + bv, 0.f);
        unsigned short hh, ll; split2(o, hh, ll);
        unsigned short* d2 = APKw + (size_t)grow*512 + 256 + (c>>5)*64 + (c&31);
        d2[0]  = hh;
        d2[32] = ll;
      }
    }
  } else {
    float ov[8][4];
    float pwv[8];
    float n2 = 0.f;
    #pragma unroll
    for (int ct=0; ct<8; ++ct){ pwv[ct] = pw[ct*16 + c16]; n2 += pwv[ct]*pwv[ct]; }
    n2 += __shfl_xor(n2,8,16); n2 += __shfl_xor(n2,4,16);
    n2 += __shfl_xor(n2,2,16); n2 += __shfl_xor(n2,1,16);
    float nrm = sqrtf(n2);
    #pragma unroll
    for (int ct=0; ct<8; ++ct){
      int c = ct*16 + c16;
      float bv = bias[c];
      #pragma unroll
      for (int r=0; r<4; ++r){
        int grow = rowBase + q*4 + r;
        float o = fmaxf(acc[ct][r] + bv, 0.f);
        OUT[(size_t)grow*DF + c] = o;
        ov[ct][r] = o;
      }
    }
    #pragma unroll
    for (int r=0; r<4; ++r){
      float p = 0.f;
      #pragma unroll
      for (int ct=0; ct<8; ++ct) p += ov[ct][r]*pwv[ct];
      p += __shfl_xor(p,8,16); p += __shfl_xor(p,4,16);
      p += __shfl_xor(p,2,16); p += __shfl_xor(p,1,16);
      if (c16 == 0) scores[rowBase + q*4 + r] = tanhf(p/nrm);
    }
  }
}

// ---------------- top-k (exact, jax tie-break) + pool + classifier ---------
__global__ __launch_bounds__(1024) void k_topk(
    const float* __restrict__ scores, const float* __restrict__ H,
    const float* __restrict__ Wc1, const float* __restrict__ bc1,
    const float* __restrict__ Wc2, const float* __restrict__ bc2,
    float* __restrict__ out)
{
  __shared__ uint64_t keys[NNODE];
  __shared__ float part[8*DF];
  __shared__ float emb[DF];
  __shared__ float hred[DF];
  const int t = threadIdx.x; const int b = blockIdx.x;
  const float* sc = scores + b*NNODE;

  for (int i=t; i<NNODE; i+=1024){
    uint32_t u = __float_as_uint(sc[i]);
    uint32_t m = (u & 0x80000000u) ? ~u : (u | 0x80000000u);
    keys[i] = ((uint64_t)(~m) << 32) | (uint32_t)i;
  }
  __syncthreads();

  for (int k=2; k<=NNODE; k<<=1){
    for (int j=k>>1; j>0; j>>=1){
      int i = ((t & ~(j-1)) << 1) | (t & (j-1));
      int p = i | j;
      uint64_t a = keys[i], c = keys[p];
      bool up = ((i & k) == 0);
      if ((a > c) == up){ keys[i] = c; keys[p] = a; }
      __syncthreads();
    }
  }

  const int pg = t >> 7, f = t & (DF-1);
  float accv = 0.f;
  for (int s2=pg; s2<KSEL; s2+=8){
    uint64_t kv = keys[s2];
    uint32_t idx = (uint32_t)kv;
    uint32_t m = ~(uint32_t)(kv >> 32);
    uint32_t u = (m & 0x80000000u) ? (m ^ 0x80000000u) : ~m;
    float val = __uint_as_float(u);
    accv += val * H[((size_t)b*NNODE + idx)*DF + f];
  }
  part[pg*DF + f] = accv;
  __syncthreads();
  if (t < DF){
    float e = 0.f;
    for (int g2=0; g2<8; ++g2) e += part[g2*DF + t];
    emb[t] = e / (float)KSEL;
  }
  __syncthreads();
  if (t < DF){
    float hv = bc1[t];
    const float* wr = Wc1 + t*DF;
    for (int f2=0; f2<DF; ++f2) hv = fmaf(emb[f2], wr[f2], hv);
    hred[t] = fmaxf(hv, 0.f) * Wc2[t];
  }
  __syncthreads();
  if (t == 0){
    float o = bc2[0];
    for (int c2=0; c2<DF; ++c2) o += hred[c2];
    out[b] = o;
  }
}

// ---------------- launch ----------------
extern "C" void kernel_launch(void* const* d_in, const int* in_sizes, int n_in,
                              void* d_out, int out_size, void* d_ws, size_t ws_size,
                              hipStream_t stream)
{
  (void)in_sizes; (void)n_in; (void)out_size; (void)ws_size;
  const float* x   = (const float*)d_in[0];
  const int* esrc  = (const int*)d_in[1];
  const int* edst  = (const int*)d_in[2];
  const float* Wl1 = (const float*)d_in[3];
  const float* bl1 = (const float*)d_in[4];
  const float* Wr1 = (const float*)d_in[5];
  const float* Wl2 = (const float*)d_in[6];
  const float* bl2 = (const float*)d_in[7];
  const float* Wr2 = (const float*)d_in[8];
  const float* pw  = (const float*)d_in[9];
  const float* Wc1 = (const float*)d_in[10];
  const float* bc1 = (const float*)d_in[11];
  const float* Wc2 = (const float*)d_in[12];
  const float* bc2 = (const float*)d_in[13];
  float* out = (float*)d_out;

  char* ws = (char*)d_ws;                       // ~104 MB used
  unsigned short* APK = (unsigned short*)(ws);  // 64MB packed operands
  float*    H2     = (float*)   (ws + 67108864);   // 32MB
  uint32_t* deg    = (uint32_t*)(ws + 100663296);  // 256KB
  uint32_t* rowptr = (uint32_t*)(ws + 100925440);  // 65537 u32
  int*      col    = (int*)     (ws + 101187840);  // 2MB
  float*    scores = (float*)   (ws + 103284992);  // 256KB
  uint32_t* bsum   = (uint32_t*)(ws + 103547136);  // 256B
  unsigned short* Bpk = (unsigned short*)(ws + 103547392); // 256KB (2 layers)

  hipMemsetAsync(deg, 0, NT*sizeof(uint32_t), stream);

  k_deg    <<<ETOT/256, 256, 0, stream>>>(edst, deg);
  k_scan1  <<<64, 1024, 0, stream>>>(deg, rowptr, bsum);
  k_scan2  <<<1, 64, 0, stream>>>(bsum);
  k_scan3  <<<64, 1024, 0, stream>>>(rowptr, bsum);
  k_scatter<<<ETOT/256, 256, 0, stream>>>(esrc, edst, rowptr, deg, col);

  k_packB<<<16, 256, 0, stream>>>(Wl1, Wr1, Bpk);
  k_packB<<<16, 256, 0, stream>>>(Wl2, Wr2, Bpk + 65536);

  // layer 1: agg(x)+pack(x) -> APK; comb reads APK, writes H1 packed in place
  k_agg<1> <<<NT/8, 256, 0, stream>>>(x, APK, rowptr, col);
  k_comb<1><<<NT/64, 256, 0, stream>>>(APK, APK, Bpk, bl1,
                                       nullptr, nullptr, nullptr);
  // layer 2: agg(H1 packed) -> APK[agg]; comb writes H2 f32 + scores
  k_agg<2> <<<NT/8, 256, 0, stream>>>(nullptr, APK, rowptr, col);
  k_comb<2><<<NT/64, 256, 0, stream>>>(APK, nullptr, Bpk + 65536, bl2,
                                       H2, pw, scores);

  k_topk<<<NB, 1024, 0, stream>>>(scores, H2, Wc1, bc1, Wc2, bc2, out);
}

// Round 4
// 203.474 us; speedup vs baseline: 1.7934x; 1.1115x over previous
//
#include <hip/hip_runtime.h>
#include <stdint.h>
#include <math.h>

// Problem constants (fixed by the reference)
#define NB    32          // graphs
#define NNODE 2048        // nodes per graph
#define NT    (NB*NNODE)  // 65536 total nodes
#define EPB   16384       // edges per graph
#define ETOT  (NB*EPB)    // 524288 edges
#define DF    128         // feature dim
#define KSEL  615         // ceil(0.3*2048)

typedef __attribute__((ext_vector_type(8))) short bf16x8;
typedef __attribute__((ext_vector_type(4))) float f32x4;

// ---- split-precision helpers: f32 ~= hi(bf16) + lo(bf16), err ~2^-17 ----
__device__ __forceinline__ unsigned short f2bf(float f){
  uint32_t u = __float_as_uint(f);
  u += 0x7FFFu + ((u>>16)&1u);                 // RNE
  return (unsigned short)(u>>16);
}
__device__ __forceinline__ void split2(float f, unsigned short& hi, unsigned short& lo){
  unsigned short h = f2bf(f);
  float fh = __uint_as_float(((uint32_t)h)<<16);
  hi = h;
  lo = f2bf(f - fh);
}
__device__ __forceinline__ float bf2f(unsigned short u){
  return __uint_as_float(((uint32_t)u)<<16);
}
// monotone u32 <-> f32 (ascending u32 == ascending float over all reals)
__device__ __forceinline__ uint32_t f2mono(float f){
  uint32_t u = __float_as_uint(f);
  return (u & 0x80000000u) ? ~u : (u | 0x80000000u);
}
__device__ __forceinline__ float mono2f(uint32_t m){
  uint32_t u = (m & 0x80000000u) ? (m ^ 0x80000000u) : ~m;
  return __uint_as_float(u);
}

// Packed operand layout (per row, 1KB = 512 ushorts): 8 k-steps of 32 feats;
// per k-step 64 shorts: [hi bf16 x32][lo bf16 x32].
// ks 0..3 = AGG features (k 0..127, Wl half), ks 4..7 = X features (Wr half).

// ---------------- CSR build ----------------
__global__ void k_deg(const int* __restrict__ edst, uint32_t* __restrict__ deg){
  int e = blockIdx.x*256 + threadIdx.x;
  int g = e >> 14;
  atomicAdd(&deg[g*NNODE + edst[e]], 1u);
}

__global__ __launch_bounds__(1024) void k_scan1(const uint32_t* __restrict__ deg,
                        uint32_t* __restrict__ rowptr, uint32_t* __restrict__ bsum){
  __shared__ uint32_t sh[1024];
  int t = threadIdx.x; int base = blockIdx.x*1024;
  uint32_t v = deg[base+t];
  sh[t] = v;
  for (int off=1; off<1024; off<<=1){
    __syncthreads();
    uint32_t a = (t>=off) ? sh[t-off] : 0u;
    __syncthreads();
    sh[t] += a;
  }
  rowptr[base+t] = sh[t] - v;
  if (t==1023) bsum[blockIdx.x] = sh[1023];
}

__global__ void k_scan2(uint32_t* __restrict__ bsum){
  __shared__ uint32_t sh[64];
  int t = threadIdx.x;
  uint32_t v = bsum[t]; sh[t] = v;
  for (int off=1; off<64; off<<=1){
    __syncthreads();
    uint32_t a = (t>=off) ? sh[t-off] : 0u;
    __syncthreads();
    sh[t] += a;
  }
  bsum[t] = sh[t] - v;
}

__global__ __launch_bounds__(1024) void k_scan3(uint32_t* __restrict__ rowptr,
                                                const uint32_t* __restrict__ bsum){
  int i = blockIdx.x*1024 + threadIdx.x;
  rowptr[i] += bsum[i>>10];
  if (i==0) rowptr[NT] = ETOT;
}

__global__ void k_scatter(const int* __restrict__ esrc, const int* __restrict__ edst,
                          const uint32_t* __restrict__ rowptr, uint32_t* __restrict__ deg,
                          int* __restrict__ col){
  int e = blockIdx.x*256 + threadIdx.x;
  int g = e >> 14;
  int d = g*NNODE + edst[e];
  int s = g*NNODE + esrc[e];
  uint32_t old = atomicSub(&deg[d], 1u);
  col[rowptr[d] + old - 1u] = s;
}

// ---------------- weight pack: B[k][c] (k<128:Wl, else Wr) -> MFMA frags ----
__global__ void k_packB(const float* __restrict__ Wl, const float* __restrict__ Wr,
                        unsigned short* __restrict__ Bpk){
  int t = blockIdx.x*256 + threadIdx.x;        // 4096 threads per layer
  int lane = t & 63;
  int ct   = (t>>6) & 7;
  int ks   = (t>>9) & 7;
  int c  = ct*16 + (lane & 15);
  int k0 = ks*32 + ((lane>>4)<<3);
  size_t base = ((size_t)((ks*8+ct)*2)*64 + lane)*8;
  #pragma unroll
  for (int j=0;j<8;++j){
    int k = k0 + j;
    float v = (k < DF) ? Wl[c*DF + k] : Wr[c*DF + (k-DF)];
    unsigned short h, l; split2(v, h, l);
    Bpk[base + j]       = h;
    Bpk[base + 512 + j] = l;                   // part=1 stride = 64*8
  }
}

// ---------------- mean aggregation -> packed agg region --------------------
// 32-lane group per node (lane c owns float4 = feats 4c..4c+3); 8 nodes/block.
// XCD swizzle: graph g = bid&31 -> dispatch ids = g (mod 32) -> XCD g%8.
// Layer 1 additionally packs the node's own x row (replaces k_pack).
template<int LAYER>
__global__ __launch_bounds__(256) void k_agg(const float* __restrict__ X,
      unsigned short* __restrict__ APK, const uint32_t* __restrict__ rowptr,
      const int* __restrict__ col){
  const int grp = threadIdx.x >> 5, c = threadIdx.x & 31;
  const int bid = blockIdx.x;
  const int g = bid & 31, jj = bid >> 5;          // 256 blocks per graph
  const int i = g*NNODE + jj*8 + grp;
  uint32_t b = rowptr[i], e = rowptr[i+1];
  float ax=0.f, ay=0.f, az=0.f, aw=0.f;

  if constexpr (LAYER==1){
    const float4* X4 = (const float4*)X;
    uint32_t k = b;
    for (; k+4<=e; k+=4){
      int s0=col[k], s1=col[k+1], s2=col[k+2], s3=col[k+3];
      float4 v0=X4[(size_t)s0*32+c], v1=X4[(size_t)s1*32+c],
             v2=X4[(size_t)s2*32+c], v3=X4[(size_t)s3*32+c];
      ax+=v0.x+v1.x+v2.x+v3.x; ay+=v0.y+v1.y+v2.y+v3.y;
      az+=v0.z+v1.z+v2.z+v3.z; aw+=v0.w+v1.w+v2.w+v3.w;
    }
    for (; k<e; ++k){
      float4 v = X4[(size_t)col[k]*32+c];
      ax+=v.x; ay+=v.y; az+=v.z; aw+=v.w;
    }
    // fused: pack own row's x into the x-region (row is L2-hot on this XCD)
    float4 xv = X4[(size_t)i*32 + c];
    unsigned short h0,l0,h1,l1,h2,l2,h3,l3;
    split2(xv.x,h0,l0); split2(xv.y,h1,l1);
    split2(xv.z,h2,l2); split2(xv.w,h3,l3);
    unsigned short* dx = APK + (size_t)i*512 + 256 + (c>>3)*64 + 4*(c&7);
    *(ushort4*)dx      = make_ushort4(h0,h1,h2,h3);
    *(ushort4*)(dx+32) = make_ushort4(l0,l1,l2,l3);
  } else {
    uint32_t k = b;
    const size_t off = 256 + (c>>3)*64 + 4*(c&7);
    for (; k+4<=e; k+=4){
      int s0=col[k], s1=col[k+1], s2=col[k+2], s3=col[k+3];
      const unsigned short* p0 = APK + (size_t)s0*512 + off;
      const unsigned short* p1 = APK + (size_t)s1*512 + off;
      const unsigned short* p2 = APK + (size_t)s2*512 + off;
      const unsigned short* p3 = APK + (size_t)s3*512 + off;
      ushort4 h0=*(const ushort4*)p0, L0=*(const ushort4*)(p0+32);
      ushort4 h1=*(const ushort4*)p1, L1=*(const ushort4*)(p1+32);
      ushort4 h2=*(const ushort4*)p2, L2=*(const ushort4*)(p2+32);
      ushort4 h3=*(const ushort4*)p3, L3=*(const ushort4*)(p3+32);
      ax += bf2f(h0.x)+bf2f(L0.x)+bf2f(h1.x)+bf2f(L1.x)+bf2f(h2.x)+bf2f(L2.x)+bf2f(h3.x)+bf2f(L3.x);
      ay += bf2f(h0.y)+bf2f(L0.y)+bf2f(h1.y)+bf2f(L1.y)+bf2f(h2.y)+bf2f(L2.y)+bf2f(h3.y)+bf2f(L3.y);
      az += bf2f(h0.z)+bf2f(L0.z)+bf2f(h1.z)+bf2f(L1.z)+bf2f(h2.z)+bf2f(L2.z)+bf2f(h3.z)+bf2f(L3.z);
      aw += bf2f(h0.w)+bf2f(L0.w)+bf2f(h1.w)+bf2f(L1.w)+bf2f(h2.w)+bf2f(L2.w)+bf2f(h3.w)+bf2f(L3.w);
    }
    for (; k<e; ++k){
      const unsigned short* p = APK + (size_t)col[k]*512 + off;
      ushort4 hv=*(const ushort4*)p, lv=*(const ushort4*)(p+32);
      ax += bf2f(hv.x)+bf2f(lv.x);
      ay += bf2f(hv.y)+bf2f(lv.y);
      az += bf2f(hv.z)+bf2f(lv.z);
      aw += bf2f(hv.w)+bf2f(lv.w);
    }
  }

  float invd = 1.0f / (float)((e>b)?(e-b):1u);
  unsigned short h0,l0,h1,l1,h2,l2,h3,l3;
  split2(ax*invd,h0,l0); split2(ay*invd,h1,l1);
  split2(az*invd,h2,l2); split2(aw*invd,h3,l3);
  unsigned short* dst = APK + (size_t)i*512 + (c>>3)*64 + 4*(c&7);
  *(ushort4*)dst      = make_ushort4(h0,h1,h2,h3);
  *(ushort4*)(dst+32) = make_ushort4(l0,l1,l2,l3);
}

// ---------------- fused SAGE combine via split-bf16 MFMA -------------------
// wave: 16 rows x 128 cols (8 ct tiles of 16x16), K=256 in 8 steps of 32.
// 3 MFMAs per (ct,ks): hi*hi + hi*lo + lo*hi.  XCD-swizzled like k_agg.
template<int LAYER>
__global__ __launch_bounds__(256) void k_comb(
    const unsigned short* __restrict__ APKc, unsigned short* __restrict__ APKw,
    const unsigned short* __restrict__ Bpk, const float* __restrict__ bias,
    float* __restrict__ OUT, const float* __restrict__ pw,
    float* __restrict__ scores)
{
  int l = threadIdx.x & 63, w = threadIdx.x >> 6;
  int g = blockIdx.x & 31, jb = blockIdx.x >> 5;   // 32 blocks per graph
  int rowBase = g*NNODE + jb*64 + w*16;
  int q = l >> 4, c16 = l & 15;
  int arow = rowBase + c16;

  f32x4 acc[8];
  #pragma unroll
  for (int ct=0; ct<8; ++ct) acc[ct] = (f32x4){0.f,0.f,0.f,0.f};

  const unsigned short* ap = APKc + (size_t)arow*512 + q*8;
  #pragma unroll 2
  for (int ks=0; ks<8; ++ks){
    bf16x8 ahi = *(const bf16x8*)(ap + ks*64);
    bf16x8 alo = *(const bf16x8*)(ap + ks*64 + 32);
    const unsigned short* bp = Bpk + (size_t)ks*8192 + l*8;
    #pragma unroll
    for (int ct=0; ct<8; ++ct){
      bf16x8 bhi = *(const bf16x8*)(bp + ct*1024);
      bf16x8 blo = *(const bf16x8*)(bp + ct*1024 + 512);
      acc[ct] = __builtin_amdgcn_mfma_f32_16x16x32_bf16(ahi, bhi, acc[ct], 0,0,0);
      acc[ct] = __builtin_amdgcn_mfma_f32_16x16x32_bf16(ahi, blo, acc[ct], 0,0,0);
      acc[ct] = __builtin_amdgcn_mfma_f32_16x16x32_bf16(alo, bhi, acc[ct], 0,0,0);
    }
  }

  __syncthreads();

  if constexpr (LAYER==1){
    #pragma unroll
    for (int ct=0; ct<8; ++ct){
      int c = ct*16 + c16;
      float bv = bias[c];
      #pragma unroll
      for (int r=0; r<4; ++r){
        int grow = rowBase + q*4 + r;
        float o = fmaxf(acc[ct][r] + bv, 0.f);
        unsigned short hh, ll; split2(o, hh, ll);
        unsigned short* d2 = APKw + (size_t)grow*512 + 256 + (c>>5)*64 + (c&31);
        d2[0]  = hh;
        d2[32] = ll;
      }
    }
  } else {
    float ov[8][4];
    float pwv[8];
    float n2 = 0.f;
    #pragma unroll
    for (int ct=0; ct<8; ++ct){ pwv[ct] = pw[ct*16 + c16]; n2 += pwv[ct]*pwv[ct]; }
    n2 += __shfl_xor(n2,8,16); n2 += __shfl_xor(n2,4,16);
    n2 += __shfl_xor(n2,2,16); n2 += __shfl_xor(n2,1,16);
    float nrm = sqrtf(n2);
    #pragma unroll
    for (int ct=0; ct<8; ++ct){
      int c = ct*16 + c16;
      float bv = bias[c];
      #pragma unroll
      for (int r=0; r<4; ++r){
        int grow = rowBase + q*4 + r;
        float o = fmaxf(acc[ct][r] + bv, 0.f);
        OUT[(size_t)grow*DF + c] = o;
        ov[ct][r] = o;
      }
    }
    #pragma unroll
    for (int r=0; r<4; ++r){
      float p = 0.f;
      #pragma unroll
      for (int ct=0; ct<8; ++ct) p += ov[ct][r]*pwv[ct];
      p += __shfl_xor(p,8,16); p += __shfl_xor(p,4,16);
      p += __shfl_xor(p,2,16); p += __shfl_xor(p,1,16);
      if (c16 == 0) scores[rowBase + q*4 + r] = tanhf(p/nrm);
    }
  }
}

// ---------------- top-k via radix-select + pool + classifier ---------------
// One block per graph. Radix-select (MSB-first, 6-bit digits) finds the exact
// 615th-largest monotone key + tie count; ties resolved by ascending index
// (== jax.lax.top_k stability). No full sort.
__global__ __launch_bounds__(1024) void k_topk(
    const float* __restrict__ scores, const float* __restrict__ H,
    const float* __restrict__ Wc1, const float* __restrict__ bc1,
    const float* __restrict__ Wc2, const float* __restrict__ bc2,
    float* __restrict__ out)
{
  __shared__ uint32_t keys[NNODE];            // 8KB monotone keys
  __shared__ uint32_t hist[64];
  __shared__ uint32_t wsum[16];               // block-scan wave sums
  __shared__ uint32_t sh_b, sh_rank, sh_cnt;
  __shared__ unsigned short selidx[KSEL+1];
  __shared__ float selval[KSEL+1];
  __shared__ float part[8*DF];
  __shared__ float emb[DF];
  __shared__ float hred[DF];

  const int t = threadIdx.x; const int b = blockIdx.x;
  const int lane = t & 63, wid = t >> 6;
  const float* sc = scores + b*NNODE;

  for (int i=t; i<NNODE; i+=1024) keys[i] = f2mono(sc[i]);
  __syncthreads();

  // ---- radix select: find threshold key T = 615th largest ----
  uint32_t prefix = 0, prefmask = 0, rank = KSEL, cntT = 0;
  #pragma unroll
  for (int lev=0; lev<6; ++lev){
    const int shift = (lev<5) ? (26 - 6*lev) : 0;
    const uint32_t bmask = (lev<5) ? 63u : 3u;
    if (t < 64) hist[t] = 0;
    __syncthreads();
    for (int i=t; i<NNODE; i+=1024){
      uint32_t k = keys[i];
      if ((k & prefmask) == prefix) atomicAdd(&hist[(k>>shift)&bmask], 1u);
    }
    __syncthreads();
    if (t < 64){
      uint32_t x = hist[t];                    // lanes >= nb hold 0 (bmask<64)
      #pragma unroll
      for (int off=1; off<64; off<<=1){        // inclusive suffix sum
        uint32_t y = __shfl_down(x, off, 64);
        if (t + off < 64) x += y;
      }
      uint32_t above = __shfl_down(x, 1, 64);
      if (t == 63) above = 0;
      if (above < rank && rank <= x){
        sh_b = (uint32_t)t; sh_rank = rank - above; sh_cnt = x - above;
      }
    }
    __syncthreads();
    prefix |= (sh_b << shift);
    prefmask |= (bmask << shift);
    rank = sh_rank; cntT = sh_cnt;
    __syncthreads();                           // sh_* consumed before next level
  }
  const uint32_t T = prefix;
  const uint32_t m = rank;                     // # of ==T keys to take (by min idx)

  // ---- selection + compaction (block scans, shfl-based) ----
  uint32_t k0 = keys[2*t], k1 = keys[2*t+1];
  uint32_t eq0 = (k0 == T), eq1 = (k1 == T);
  uint32_t eqr0 = 0, eqr1 = 0;

  if (m != cntT){                              // boundary duplicates: rank them
    uint32_t v = eq0 + eq1, x = v;
    #pragma unroll
    for (int off=1; off<64; off<<=1){
      uint32_t y = __shfl_up(x, off, 64);
      if (lane >= off) x += y;
    }
    if (lane == 63) wsum[wid] = x;
    __syncthreads();
    if (wid == 0){
      uint32_t s = (lane < 16) ? wsum[lane] : 0;
      #pragma unroll
      for (int off=1; off<16; off<<=1){
        uint32_t y = __shfl_up(s, off, 64);
        if (lane >= off) s += y;
      }
      if (lane < 16) wsum[lane] = s;
    }
    __syncthreads();
    uint32_t excl = (wid ? wsum[wid-1] : 0) + x - v;
    eqr0 = excl; eqr1 = excl + eq0;
    __syncthreads();                           // wsum reused below
  }

  uint32_t sel0 = (k0 > T) || (eq0 && eqr0 < m);
  uint32_t sel1 = (k1 > T) || (eq1 && eqr1 < m);
  {
    uint32_t v = sel0 + sel1, x = v;
    #pragma unroll
    for (int off=1; off<64; off<<=1){
      uint32_t y = __shfl_up(x, off, 64);
      if (lane >= off) x += y;
    }
    if (lane == 63) wsum[wid] = x;
    __syncthreads();
    if (wid == 0){
      uint32_t s = (lane < 16) ? wsum[lane] : 0;
      #pragma unroll
      for (int off=1; off<16; off<<=1){
        uint32_t y = __shfl_up(s, off, 64);
        if (lane >= off) s += y;
      }
      if (lane < 16) wsum[lane] = s;
    }
    __syncthreads();
    uint32_t excl = (wid ? wsum[wid-1] : 0) + x - v;
    if (sel0){ selidx[excl] = (unsigned short)(2*t);   selval[excl] = mono2f(k0); }
    if (sel1){ selidx[excl+sel0] = (unsigned short)(2*t+1); selval[excl+sel0] = mono2f(k1); }
  }
  __syncthreads();

  // ---- gated mean over the 615 selected rows (4-deep unrolled gather) ----
  const int pg = t >> 7, f = t & (DF-1);
  const float* Hb = H + (size_t)b*NNODE*DF;
  float accv = 0.f;
  int s2 = pg;
  for (; s2+24 < KSEL; s2 += 32){
    int i0=selidx[s2], i1=selidx[s2+8], i2=selidx[s2+16], i3=selidx[s2+24];
    float w0=selval[s2], w1=selval[s2+8], w2=selval[s2+16], w3=selval[s2+24];
    float v0=Hb[(size_t)i0*DF+f], v1=Hb[(size_t)i1*DF+f],
          v2=Hb[(size_t)i2*DF+f], v3=Hb[(size_t)i3*DF+f];
    accv += w0*v0 + w1*v1 + w2*v2 + w3*v3;
  }
  for (; s2<KSEL; s2+=8) accv += selval[s2]*Hb[(size_t)selidx[s2]*DF+f];
  part[pg*DF + f] = accv;
  __syncthreads();
  if (t < DF){
    float e = 0.f;
    for (int g2=0; g2<8; ++g2) e += part[g2*DF + t];
    emb[t] = e / (float)KSEL;
  }
  __syncthreads();
  if (t < DF){
    float hv = bc1[t];
    const float* wr = Wc1 + t*DF;
    for (int f2=0; f2<DF; ++f2) hv = fmaf(emb[f2], wr[f2], hv);
    hred[t] = fmaxf(hv, 0.f) * Wc2[t];
  }
  __syncthreads();
  if (t == 0){
    float o = bc2[0];
    for (int c2=0; c2<DF; ++c2) o += hred[c2];
    out[b] = o;
  }
}

// ---------------- launch ----------------
extern "C" void kernel_launch(void* const* d_in, const int* in_sizes, int n_in,
                              void* d_out, int out_size, void* d_ws, size_t ws_size,
                              hipStream_t stream)
{
  (void)in_sizes; (void)n_in; (void)out_size; (void)ws_size;
  const float* x   = (const float*)d_in[0];
  const int* esrc  = (const int*)d_in[1];
  const int* edst  = (const int*)d_in[2];
  const float* Wl1 = (const float*)d_in[3];
  const float* bl1 = (const float*)d_in[4];
  const float* Wr1 = (const float*)d_in[5];
  const float* Wl2 = (const float*)d_in[6];
  const float* bl2 = (const float*)d_in[7];
  const float* Wr2 = (const float*)d_in[8];
  const float* pw  = (const float*)d_in[9];
  const float* Wc1 = (const float*)d_in[10];
  const float* bc1 = (const float*)d_in[11];
  const float* Wc2 = (const float*)d_in[12];
  const float* bc2 = (const float*)d_in[13];
  float* out = (float*)d_out;

  char* ws = (char*)d_ws;                       // ~104 MB used
  unsigned short* APK = (unsigned short*)(ws);  // 64MB packed operands
  float*    H2     = (float*)   (ws + 67108864);   // 32MB
  uint32_t* deg    = (uint32_t*)(ws + 100663296);  // 256KB
  uint32_t* rowptr = (uint32_t*)(ws + 100925440);  // 65537 u32
  int*      col    = (int*)     (ws + 101187840);  // 2MB
  float*    scores = (float*)   (ws + 103284992);  // 256KB
  uint32_t* bsum   = (uint32_t*)(ws + 103547136);  // 256B
  unsigned short* Bpk = (unsigned short*)(ws + 103547392); // 256KB (2 layers)

  hipMemsetAsync(deg, 0, NT*sizeof(uint32_t), stream);

  k_deg    <<<ETOT/256, 256, 0, stream>>>(edst, deg);
  k_scan1  <<<64, 1024, 0, stream>>>(deg, rowptr, bsum);
  k_scan2  <<<1, 64, 0, stream>>>(bsum);
  k_scan3  <<<64, 1024, 0, stream>>>(rowptr, bsum);
  k_scatter<<<ETOT/256, 256, 0, stream>>>(esrc, edst, rowptr, deg, col);

  k_packB<<<16, 256, 0, stream>>>(Wl1, Wr1, Bpk);
  k_packB<<<16, 256, 0, stream>>>(Wl2, Wr2, Bpk + 65536);

  // layer 1: agg(x)+pack(x) -> APK; comb reads APK, writes H1 packed in place
  k_agg<1> <<<NT/8, 256, 0, stream>>>(x, APK, rowptr, col);
  k_comb<1><<<NT/64, 256, 0, stream>>>(APK, APK, Bpk, bl1,
                                       nullptr, nullptr, nullptr);
  // layer 2: agg(H1 packed) -> APK[agg]; comb writes H2 f32 + scores
  k_agg<2> <<<NT/8, 256, 0, stream>>>(nullptr, APK, rowptr, col);
  k_comb<2><<<NT/64, 256, 0, stream>>>(APK, nullptr, Bpk + 65536, bl2,
                                       H2, pw, scores);

  k_topk<<<NB, 1024, 0, stream>>>(scores, H2, Wc1, bc1, Wc2, bc2, out);
}

// Round 5
// 176.817 us; speedup vs baseline: 2.0638x; 1.1508x over previous
//
#include <hip/hip_runtime.h>
#include <stdint.h>
#include <math.h>

// Problem constants (fixed by the reference)
#define NB    32          // graphs
#define NNODE 2048        // nodes per graph
#define NT    (NB*NNODE)  // 65536 total nodes
#define EPB   16384       // edges per graph
#define ETOT  (NB*EPB)    // 524288 edges
#define DF    128         // feature dim
#define KSEL  615         // ceil(0.3*2048)

typedef __attribute__((ext_vector_type(8))) short bf16x8;
typedef __attribute__((ext_vector_type(4))) float f32x4;

// ---- split-precision helpers: f32 ~= hi(bf16) + lo(bf16), err ~2^-17 ----
__device__ __forceinline__ unsigned short f2bf(float f){
  uint32_t u = __float_as_uint(f);
  u += 0x7FFFu + ((u>>16)&1u);                 // RNE
  return (unsigned short)(u>>16);
}
__device__ __forceinline__ void split2(float f, unsigned short& hi, unsigned short& lo){
  unsigned short h = f2bf(f);
  float fh = __uint_as_float(((uint32_t)h)<<16);
  hi = h;
  lo = f2bf(f - fh);
}
// monotone u32 <-> f32 (ascending u32 == ascending float over all reals)
__device__ __forceinline__ uint32_t f2mono(float f){
  uint32_t u = __float_as_uint(f);
  return (u & 0x80000000u) ? ~u : (u | 0x80000000u);
}
__device__ __forceinline__ float mono2f(uint32_t m){
  uint32_t u = (m & 0x80000000u) ? (m ^ 0x80000000u) : ~m;
  return __uint_as_float(u);
}

// ---------------- CSR build ----------------
__global__ void k_deg(const int* __restrict__ edst, uint32_t* __restrict__ deg){
  int e = blockIdx.x*256 + threadIdx.x;
  int g = e >> 14;
  atomicAdd(&deg[g*NNODE + edst[e]], 1u);
}

__global__ __launch_bounds__(1024) void k_scan1(const uint32_t* __restrict__ deg,
                        uint32_t* __restrict__ rowptr, uint32_t* __restrict__ bsum){
  __shared__ uint32_t sh[1024];
  int t = threadIdx.x; int base = blockIdx.x*1024;
  uint32_t v = deg[base+t];
  sh[t] = v;
  for (int off=1; off<1024; off<<=1){
    __syncthreads();
    uint32_t a = (t>=off) ? sh[t-off] : 0u;
    __syncthreads();
    sh[t] += a;
  }
  rowptr[base+t] = sh[t] - v;
  if (t==1023) bsum[blockIdx.x] = sh[1023];
}

__global__ void k_scan2(uint32_t* __restrict__ bsum){
  __shared__ uint32_t sh[64];
  int t = threadIdx.x;
  uint32_t v = bsum[t]; sh[t] = v;
  for (int off=1; off<64; off<<=1){
    __syncthreads();
    uint32_t a = (t>=off) ? sh[t-off] : 0u;
    __syncthreads();
    sh[t] += a;
  }
  bsum[t] = sh[t] - v;
}

__global__ __launch_bounds__(1024) void k_scan3(uint32_t* __restrict__ rowptr,
                                                const uint32_t* __restrict__ bsum){
  int i = blockIdx.x*1024 + threadIdx.x;
  rowptr[i] += bsum[i>>10];
  if (i==0) rowptr[NT] = ETOT;
}

__global__ void k_scatter(const int* __restrict__ esrc, const int* __restrict__ edst,
                          const uint32_t* __restrict__ rowptr, uint32_t* __restrict__ deg,
                          int* __restrict__ col){
  int e = blockIdx.x*256 + threadIdx.x;
  int g = e >> 14;
  int d = g*NNODE + edst[e];
  int s = g*NNODE + esrc[e];
  uint32_t old = atomicSub(&deg[d], 1u);
  col[rowptr[d] + old - 1u] = s;
}

// ---------------- weight pack: B[k][c] (k<128:Wl, else Wr) -> MFMA frags ----
// Bpk elem offset: ks*8192 + ct*1024 + part*512 + lane*8 + j
__global__ void k_packB(const float* __restrict__ Wl, const float* __restrict__ Wr,
                        unsigned short* __restrict__ Bpk){
  int t = blockIdx.x*256 + threadIdx.x;        // 4096 threads per layer
  int lane = t & 63;
  int ct   = (t>>6) & 7;
  int ks   = (t>>9) & 7;
  int c  = ct*16 + (lane & 15);
  int k0 = ks*32 + ((lane>>4)<<3);
  size_t base = ((size_t)((ks*8+ct)*2)*64 + lane)*8;
  #pragma unroll
  for (int j=0;j<8;++j){
    int k = k0 + j;
    float v = (k < DF) ? Wl[c*DF + k] : Wr[c*DF + (k-DF)];
    unsigned short h, l; split2(v, h, l);
    Bpk[base + j]       = h;
    Bpk[base + 512 + j] = l;                   // part=1 stride = 64*8
  }
}

// ---------------- fused SAGE layer: agg(gather+mean) + split-bf16 MFMA -----
// 128 threads, 32 rows/block. Phase 1: 4 groups x 32 lanes gather neighbor
// rows (f32) -> mean -> LDS [32][132]. Phase 2: 2 waves x 16 rows each,
// K=256 (ks 0..3 = agg from LDS, ks 4..7 = own row from global), 3 MFMAs
// (hi*hi + hi*lo + lo*hi) per (ct,ks). XCD swizzle: graph = bid&31.
template<int LAYER>
__global__ __launch_bounds__(128) void k_sage(
    const float* __restrict__ Xin, const uint32_t* __restrict__ rowptr,
    const int* __restrict__ col, const unsigned short* __restrict__ Bpk,
    const float* __restrict__ bias, float* __restrict__ OUT,
    const float* __restrict__ pw, float* __restrict__ scores)
{
  __shared__ float smemA[32][132];             // 16.9KB, +4 float pad per row

  const int t = threadIdx.x;
  const int g = blockIdx.x & 31, jb = blockIdx.x >> 5;   // 64 blocks/graph
  const int rowBase = g*NNODE + jb*32;

  // ---- phase 1: gather + mean ----
  {
    const int grp = t >> 5, c = t & 31;
    const float4* X4 = (const float4*)Xin;
    for (int n=grp; n<32; n+=4){
      const int i = rowBase + n;
      uint32_t b = rowptr[i], e = rowptr[i+1];
      float ax=0.f, ay=0.f, az=0.f, aw=0.f;
      uint32_t k = b;
      for (; k+4<=e; k+=4){
        int s0=col[k], s1=col[k+1], s2=col[k+2], s3=col[k+3];
        float4 v0=X4[(size_t)s0*32+c], v1=X4[(size_t)s1*32+c],
               v2=X4[(size_t)s2*32+c], v3=X4[(size_t)s3*32+c];
        ax+=v0.x+v1.x+v2.x+v3.x; ay+=v0.y+v1.y+v2.y+v3.y;
        az+=v0.z+v1.z+v2.z+v3.z; aw+=v0.w+v1.w+v2.w+v3.w;
      }
      for (; k<e; ++k){
        float4 v = X4[(size_t)col[k]*32+c];
        ax+=v.x; ay+=v.y; az+=v.z; aw+=v.w;
      }
      float invd = 1.0f / (float)((e>b)?(e-b):1u);
      *(float4*)&smemA[n][4*c] = make_float4(ax*invd, ay*invd, az*invd, aw*invd);
    }
  }
  __syncthreads();

  // ---- phase 2: MFMA ----
  const int l = t & 63, wid = t >> 6;
  const int q = l >> 4, c16 = l & 15;
  const int arow = rowBase + wid*16 + c16;

  f32x4 acc[8];
  #pragma unroll
  for (int ct=0; ct<8; ++ct) acc[ct] = (f32x4){0.f,0.f,0.f,0.f};

  #pragma unroll
  for (int ks=0; ks<8; ++ks){
    float4 A0, A1;
    if (ks < 4){
      const float* s = &smemA[wid*16 + c16][ks*32 + q*8];
      A0 = *(const float4*)s; A1 = *(const float4*)(s+4);
    } else {
      const float* s = Xin + (size_t)arow*DF + (ks-4)*32 + q*8;
      A0 = *(const float4*)s; A1 = *(const float4*)(s+4);
    }
    float v[8] = {A0.x,A0.y,A0.z,A0.w,A1.x,A1.y,A1.z,A1.w};
    bf16x8 ahi, alo;
    #pragma unroll
    for (int j=0;j<8;++j){
      unsigned short h, lo_; split2(v[j], h, lo_);
      ahi[j] = (short)h; alo[j] = (short)lo_;
    }
    const unsigned short* bp = Bpk + (size_t)ks*8192 + l*8;
    #pragma unroll
    for (int ct=0; ct<8; ++ct){
      bf16x8 bhi = *(const bf16x8*)(bp + ct*1024);
      bf16x8 blo = *(const bf16x8*)(bp + ct*1024 + 512);
      acc[ct] = __builtin_amdgcn_mfma_f32_16x16x32_bf16(ahi, bhi, acc[ct], 0,0,0);
      acc[ct] = __builtin_amdgcn_mfma_f32_16x16x32_bf16(ahi, blo, acc[ct], 0,0,0);
      acc[ct] = __builtin_amdgcn_mfma_f32_16x16x32_bf16(alo, bhi, acc[ct], 0,0,0);
    }
  }

  // ---- epilogue ----
  const int rowOut = rowBase + wid*16;
  if constexpr (LAYER==1){
    #pragma unroll
    for (int ct=0; ct<8; ++ct){
      int c = ct*16 + c16;
      float bv = bias[c];
      #pragma unroll
      for (int r=0; r<4; ++r){
        int grow = rowOut + q*4 + r;
        OUT[(size_t)grow*DF + c] = fmaxf(acc[ct][r] + bv, 0.f);
      }
    }
  } else {
    float ov[8][4];
    float pwv[8];
    float n2 = 0.f;
    #pragma unroll
    for (int ct=0; ct<8; ++ct){ pwv[ct] = pw[ct*16 + c16]; n2 += pwv[ct]*pwv[ct]; }
    n2 += __shfl_xor(n2,8,16); n2 += __shfl_xor(n2,4,16);
    n2 += __shfl_xor(n2,2,16); n2 += __shfl_xor(n2,1,16);
    float nrm = sqrtf(n2);
    #pragma unroll
    for (int ct=0; ct<8; ++ct){
      int c = ct*16 + c16;
      float bv = bias[c];
      #pragma unroll
      for (int r=0; r<4; ++r){
        int grow = rowOut + q*4 + r;
        float o = fmaxf(acc[ct][r] + bv, 0.f);
        OUT[(size_t)grow*DF + c] = o;
        ov[ct][r] = o;
      }
    }
    #pragma unroll
    for (int r=0; r<4; ++r){
      float p = 0.f;
      #pragma unroll
      for (int ct=0; ct<8; ++ct) p += ov[ct][r]*pwv[ct];
      p += __shfl_xor(p,8,16); p += __shfl_xor(p,4,16);
      p += __shfl_xor(p,2,16); p += __shfl_xor(p,1,16);
      if (c16 == 0) scores[rowOut + q*4 + r] = tanhf(p/nrm);
    }
  }
}

// ---------------- top-k via radix-select + pool + classifier ---------------
__global__ __launch_bounds__(1024) void k_topk(
    const float* __restrict__ scores, const float* __restrict__ H,
    const float* __restrict__ Wc1, const float* __restrict__ bc1,
    const float* __restrict__ Wc2, const float* __restrict__ bc2,
    float* __restrict__ out)
{
  __shared__ uint32_t keys[NNODE];            // 8KB monotone keys
  __shared__ uint32_t hist[64];
  __shared__ uint32_t wsum[16];               // block-scan wave sums
  __shared__ uint32_t sh_b, sh_rank, sh_cnt;
  __shared__ unsigned short selidx[KSEL+1];
  __shared__ float selval[KSEL+1];
  __shared__ float part[8*DF];
  __shared__ float emb[DF];
  __shared__ float hred[DF];

  const int t = threadIdx.x; const int b = blockIdx.x;
  const int lane = t & 63, wid = t >> 6;
  const float* sc = scores + b*NNODE;

  for (int i=t; i<NNODE; i+=1024) keys[i] = f2mono(sc[i]);
  __syncthreads();

  // ---- radix select: find threshold key T = 615th largest ----
  uint32_t prefix = 0, prefmask = 0, rank = KSEL, cntT = 0;
  #pragma unroll
  for (int lev=0; lev<6; ++lev){
    const int shift = (lev<5) ? (26 - 6*lev) : 0;
    const uint32_t bmask = (lev<5) ? 63u : 3u;
    if (t < 64) hist[t] = 0;
    __syncthreads();
    for (int i=t; i<NNODE; i+=1024){
      uint32_t k = keys[i];
      if ((k & prefmask) == prefix) atomicAdd(&hist[(k>>shift)&bmask], 1u);
    }
    __syncthreads();
    if (t < 64){
      uint32_t x = hist[t];
      #pragma unroll
      for (int off=1; off<64; off<<=1){        // inclusive suffix sum
        uint32_t y = __shfl_down(x, off, 64);
        if (t + off < 64) x += y;
      }
      uint32_t above = __shfl_down(x, 1, 64);
      if (t == 63) above = 0;
      if (above < rank && rank <= x){
        sh_b = (uint32_t)t; sh_rank = rank - above; sh_cnt = x - above;
      }
    }
    __syncthreads();
    prefix |= (sh_b << shift);
    prefmask |= (bmask << shift);
    rank = sh_rank; cntT = sh_cnt;
    __syncthreads();
  }
  const uint32_t T = prefix;
  const uint32_t m = rank;

  // ---- selection + compaction (block scans, shfl-based) ----
  uint32_t k0 = keys[2*t], k1 = keys[2*t+1];
  uint32_t eq0 = (k0 == T), eq1 = (k1 == T);
  uint32_t eqr0 = 0, eqr1 = 0;

  if (m != cntT){
    uint32_t v = eq0 + eq1, x = v;
    #pragma unroll
    for (int off=1; off<64; off<<=1){
      uint32_t y = __shfl_up(x, off, 64);
      if (lane >= off) x += y;
    }
    if (lane == 63) wsum[wid] = x;
    __syncthreads();
    if (wid == 0){
      uint32_t s = (lane < 16) ? wsum[lane] : 0;
      #pragma unroll
      for (int off=1; off<16; off<<=1){
        uint32_t y = __shfl_up(s, off, 64);
        if (lane >= off) s += y;
      }
      if (lane < 16) wsum[lane] = s;
    }
    __syncthreads();
    uint32_t excl = (wid ? wsum[wid-1] : 0) + x - v;
    eqr0 = excl; eqr1 = excl + eq0;
    __syncthreads();
  }

  uint32_t sel0 = (k0 > T) || (eq0 && eqr0 < m);
  uint32_t sel1 = (k1 > T) || (eq1 && eqr1 < m);
  {
    uint32_t v = sel0 + sel1, x = v;
    #pragma unroll
    for (int off=1; off<64; off<<=1){
      uint32_t y = __shfl_up(x, off, 64);
      if (lane >= off) x += y;
    }
    if (lane == 63) wsum[wid] = x;
    __syncthreads();
    if (wid == 0){
      uint32_t s = (lane < 16) ? wsum[lane] : 0;
      #pragma unroll
      for (int off=1; off<16; off<<=1){
        uint32_t y = __shfl_up(s, off, 64);
        if (lane >= off) s += y;
      }
      if (lane < 16) wsum[lane] = s;
    }
    __syncthreads();
    uint32_t excl = (wid ? wsum[wid-1] : 0) + x - v;
    if (sel0){ selidx[excl] = (unsigned short)(2*t);   selval[excl] = mono2f(k0); }
    if (sel1){ selidx[excl+sel0] = (unsigned short)(2*t+1); selval[excl+sel0] = mono2f(k1); }
  }
  __syncthreads();

  // ---- gated mean over the 615 selected rows (4-deep unrolled gather) ----
  const int pg = t >> 7, f = t & (DF-1);
  const float* Hb = H + (size_t)b*NNODE*DF;
  float accv = 0.f;
  int s2 = pg;
  for (; s2+24 < KSEL; s2 += 32){
    int i0=selidx[s2], i1=selidx[s2+8], i2=selidx[s2+16], i3=selidx[s2+24];
    float w0=selval[s2], w1=selval[s2+8], w2=selval[s2+16], w3=selval[s2+24];
    float v0=Hb[(size_t)i0*DF+f], v1=Hb[(size_t)i1*DF+f],
          v2=Hb[(size_t)i2*DF+f], v3=Hb[(size_t)i3*DF+f];
    accv += w0*v0 + w1*v1 + w2*v2 + w3*v3;
  }
  for (; s2<KSEL; s2+=8) accv += selval[s2]*Hb[(size_t)selidx[s2]*DF+f];
  part[pg*DF + f] = accv;
  __syncthreads();
  if (t < DF){
    float e = 0.f;
    for (int g2=0; g2<8; ++g2) e += part[g2*DF + t];
    emb[t] = e / (float)KSEL;
  }
  __syncthreads();
  if (t < DF){
    float hv = bc1[t];
    const float* wr = Wc1 + t*DF;
    for (int f2=0; f2<DF; ++f2) hv = fmaf(emb[f2], wr[f2], hv);
    hred[t] = fmaxf(hv, 0.f) * Wc2[t];
  }
  __syncthreads();
  if (t == 0){
    float o = bc2[0];
    for (int c2=0; c2<DF; ++c2) o += hred[c2];
    out[b] = o;
  }
}

// ---------------- launch ----------------
extern "C" void kernel_launch(void* const* d_in, const int* in_sizes, int n_in,
                              void* d_out, int out_size, void* d_ws, size_t ws_size,
                              hipStream_t stream)
{
  (void)in_sizes; (void)n_in; (void)out_size; (void)ws_size;
  const float* x   = (const float*)d_in[0];
  const int* esrc  = (const int*)d_in[1];
  const int* edst  = (const int*)d_in[2];
  const float* Wl1 = (const float*)d_in[3];
  const float* bl1 = (const float*)d_in[4];
  const float* Wr1 = (const float*)d_in[5];
  const float* Wl2 = (const float*)d_in[6];
  const float* bl2 = (const float*)d_in[7];
  const float* Wr2 = (const float*)d_in[8];
  const float* pw  = (const float*)d_in[9];
  const float* Wc1 = (const float*)d_in[10];
  const float* bc1 = (const float*)d_in[11];
  const float* Wc2 = (const float*)d_in[12];
  const float* bc2 = (const float*)d_in[13];
  float* out = (float*)d_out;

  char* ws = (char*)d_ws;                       // ~70.3 MB used
  float*    H1     = (float*)   (ws + 0);          // 32MB
  float*    H2     = (float*)   (ws + 33554432);   // 32MB
  uint32_t* deg    = (uint32_t*)(ws + 67108864);   // 256KB
  uint32_t* rowptr = (uint32_t*)(ws + 67371008);   // 65537 u32
  int*      col    = (int*)     (ws + 67633408);   // 2MB
  float*    scores = (float*)   (ws + 69730560);   // 256KB
  uint32_t* bsum   = (uint32_t*)(ws + 69992704);   // 256B
  unsigned short* Bpk = (unsigned short*)(ws + 69992960); // 256KB (2 layers)

  hipMemsetAsync(deg, 0, NT*sizeof(uint32_t), stream);

  k_deg    <<<ETOT/256, 256, 0, stream>>>(edst, deg);
  k_scan1  <<<64, 1024, 0, stream>>>(deg, rowptr, bsum);
  k_scan2  <<<1, 64, 0, stream>>>(bsum);
  k_scan3  <<<64, 1024, 0, stream>>>(rowptr, bsum);
  k_scatter<<<ETOT/256, 256, 0, stream>>>(esrc, edst, rowptr, deg, col);

  k_packB<<<16, 256, 0, stream>>>(Wl1, Wr1, Bpk);
  k_packB<<<16, 256, 0, stream>>>(Wl2, Wr2, Bpk + 65536);

  // fused layers: gather+mean+GEMM per block
  k_sage<1><<<NT/32, 128, 0, stream>>>(x,  rowptr, col, Bpk,         bl1,
                                       H1, nullptr, nullptr);
  k_sage<2><<<NT/32, 128, 0, stream>>>(H1, rowptr, col, Bpk + 65536, bl2,
                                       H2, pw, scores);

  k_topk<<<NB, 1024, 0, stream>>>(scores, H2, Wc1, bc1, Wc2, bc2, out);
}

// Round 6
// 161.321 us; speedup vs baseline: 2.2620x; 1.0961x over previous
//
#include <hip/hip_runtime.h>
#include <stdint.h>
#include <math.h>

// Problem constants (fixed by the reference)
#define NB    32          // graphs
#define NNODE 2048        // nodes per graph
#define NT    (NB*NNODE)  // 65536 total nodes
#define EPB   16384       // edges per graph
#define ETOT  (NB*EPB)    // 524288 edges
#define DF    128         // feature dim
#define KSEL  615         // ceil(0.3*2048)
#define EMAX  512         // LDS-staged edge cap per 32-row tile (mean 256, sd 16)

typedef __attribute__((ext_vector_type(8))) short bf16x8;
typedef __attribute__((ext_vector_type(4))) float f32x4;

// ---- split-precision helpers: f32 ~= hi(bf16) + lo(bf16), err ~2^-17 ----
__device__ __forceinline__ unsigned short f2bf(float f){
  uint32_t u = __float_as_uint(f);
  u += 0x7FFFu + ((u>>16)&1u);                 // RNE
  return (unsigned short)(u>>16);
}
__device__ __forceinline__ void split2(float f, unsigned short& hi, unsigned short& lo){
  unsigned short h = f2bf(f);
  float fh = __uint_as_float(((uint32_t)h)<<16);
  hi = h;
  lo = f2bf(f - fh);
}
// monotone u32 <-> f32 (ascending u32 == ascending float over all reals)
__device__ __forceinline__ uint32_t f2mono(float f){
  uint32_t u = __float_as_uint(f);
  return (u & 0x80000000u) ? ~u : (u | 0x80000000u);
}
__device__ __forceinline__ float mono2f(uint32_t m){
  uint32_t u = (m & 0x80000000u) ? (m ^ 0x80000000u) : ~m;
  return __uint_as_float(u);
}

// ---------------- CSR build ----------------
__global__ void k_deg(const int* __restrict__ edst, uint32_t* __restrict__ deg){
  int e = blockIdx.x*256 + threadIdx.x;
  int g = e >> 14;
  atomicAdd(&deg[g*NNODE + edst[e]], 1u);
}

__global__ __launch_bounds__(1024) void k_scan1(const uint32_t* __restrict__ deg,
                        uint32_t* __restrict__ rowptr, uint32_t* __restrict__ bsum){
  __shared__ uint32_t sh[1024];
  int t = threadIdx.x; int base = blockIdx.x*1024;
  uint32_t v = deg[base+t];
  sh[t] = v;
  for (int off=1; off<1024; off<<=1){
    __syncthreads();
    uint32_t a = (t>=off) ? sh[t-off] : 0u;
    __syncthreads();
    sh[t] += a;
  }
  rowptr[base+t] = sh[t] - v;
  if (t==1023) bsum[blockIdx.x] = sh[1023];
}

__global__ void k_scan2(uint32_t* __restrict__ bsum){
  __shared__ uint32_t sh[64];
  int t = threadIdx.x;
  uint32_t v = bsum[t]; sh[t] = v;
  for (int off=1; off<64; off<<=1){
    __syncthreads();
    uint32_t a = (t>=off) ? sh[t-off] : 0u;
    __syncthreads();
    sh[t] += a;
  }
  bsum[t] = sh[t] - v;
}

__global__ __launch_bounds__(1024) void k_scan3(uint32_t* __restrict__ rowptr,
                                                const uint32_t* __restrict__ bsum){
  int i = blockIdx.x*1024 + threadIdx.x;
  rowptr[i] += bsum[i>>10];
  if (i==0) rowptr[NT] = ETOT;
}

__global__ void k_scatter(const int* __restrict__ esrc, const int* __restrict__ edst,
                          const uint32_t* __restrict__ rowptr, uint32_t* __restrict__ deg,
                          int* __restrict__ col){
  int e = blockIdx.x*256 + threadIdx.x;
  int g = e >> 14;
  int d = g*NNODE + edst[e];
  int s = g*NNODE + esrc[e];
  uint32_t old = atomicSub(&deg[d], 1u);
  col[rowptr[d] + old - 1u] = s;
}

// ---------------- weight pack: B[k][c] (k<128:Wl, else Wr) -> MFMA frags ----
// Bpk elem offset: ks*8192 + ct*1024 + part*512 + lane*8 + j
__global__ void k_packB(const float* __restrict__ Wl, const float* __restrict__ Wr,
                        unsigned short* __restrict__ Bpk){
  int t = blockIdx.x*256 + threadIdx.x;        // 4096 threads per layer
  int lane = t & 63;
  int ct   = (t>>6) & 7;
  int ks   = (t>>9) & 7;
  int c  = ct*16 + (lane & 15);
  int k0 = ks*32 + ((lane>>4)<<3);
  size_t base = ((size_t)((ks*8+ct)*2)*64 + lane)*8;
  #pragma unroll
  for (int j=0;j<8;++j){
    int k = k0 + j;
    float v = (k < DF) ? Wl[c*DF + k] : Wr[c*DF + (k-DF)];
    unsigned short h, l; split2(v, h, l);
    Bpk[base + j]       = h;
    Bpk[base + 512 + j] = l;                   // part=1 stride = 64*8
  }
}

// ---------------- fused SAGE layer: agg(gather+mean) + split-bf16 MFMA -----
// 128 threads, 32 rows/block. Phase 0: stage block's CSR slice (col+rowptr)
// into LDS (coalesced). Phase 1: 4 groups x 32 lanes gather neighbor rows
// (8-deep ILP, index reads from LDS) -> mean -> LDS [32][132]. Phase 2:
// 2 waves x 16 rows, K=256 (ks 0..3 agg from LDS, ks 4..7 own row from
// global), 3 MFMAs (hi*hi+hi*lo+lo*hi) per (ct,ks). XCD swizzle: bid&31.
template<int LAYER>
__global__ __launch_bounds__(128, 4) void k_sage(
    const float* __restrict__ Xin, const uint32_t* __restrict__ rowptr,
    const int* __restrict__ col, const unsigned short* __restrict__ Bpk,
    const float* __restrict__ bias, float* __restrict__ OUT,
    const float* __restrict__ pw, float* __restrict__ scores)
{
  __shared__ float smemA[32][132];             // 16.9KB, +4 float pad per row
  __shared__ int lcol[EMAX];                   // 2KB staged edge indices
  __shared__ uint32_t lrp[33];

  const int t = threadIdx.x;
  const int g = blockIdx.x & 31, jb = blockIdx.x >> 5;   // 64 blocks/graph
  const int rowBase = g*NNODE + jb*32;

  // ---- phase 0: stage CSR slice ----
  if (t < 33) lrp[t] = rowptr[rowBase + t];
  const uint32_t e0 = rowptr[rowBase];
  const int ecnt = (int)(rowptr[rowBase + 32] - e0);
  for (int i=t; i<ecnt && i<EMAX; i+=128) lcol[i] = col[e0+i];
  __syncthreads();

  // ---- phase 1: gather + mean (8-deep unrolled, LDS indices) ----
  {
    const int grp = t >> 5, c = t & 31;
    const float4* X4 = (const float4*)Xin;
    auto gather = [&](auto colAt){
      for (int n=grp; n<32; n+=4){
        uint32_t b = lrp[n] - e0, e = lrp[n+1] - e0;
        float ax=0.f, ay=0.f, az=0.f, aw=0.f;
        uint32_t k = b;
        for (; k+8<=e; k+=8){
          int s0=colAt(k),  s1=colAt(k+1), s2=colAt(k+2), s3=colAt(k+3),
              s4=colAt(k+4),s5=colAt(k+5), s6=colAt(k+6), s7=colAt(k+7);
          float4 v0=X4[(size_t)s0*32+c], v1=X4[(size_t)s1*32+c],
                 v2=X4[(size_t)s2*32+c], v3=X4[(size_t)s3*32+c],
                 v4=X4[(size_t)s4*32+c], v5=X4[(size_t)s5*32+c],
                 v6=X4[(size_t)s6*32+c], v7=X4[(size_t)s7*32+c];
          ax += ((v0.x+v1.x)+(v2.x+v3.x)) + ((v4.x+v5.x)+(v6.x+v7.x));
          ay += ((v0.y+v1.y)+(v2.y+v3.y)) + ((v4.y+v5.y)+(v6.y+v7.y));
          az += ((v0.z+v1.z)+(v2.z+v3.z)) + ((v4.z+v5.z)+(v6.z+v7.z));
          aw += ((v0.w+v1.w)+(v2.w+v3.w)) + ((v4.w+v5.w)+(v6.w+v7.w));
        }
        for (; k+4<=e; k+=4){
          int s0=colAt(k), s1=colAt(k+1), s2=colAt(k+2), s3=colAt(k+3);
          float4 v0=X4[(size_t)s0*32+c], v1=X4[(size_t)s1*32+c],
                 v2=X4[(size_t)s2*32+c], v3=X4[(size_t)s3*32+c];
          ax += (v0.x+v1.x)+(v2.x+v3.x);
          ay += (v0.y+v1.y)+(v2.y+v3.y);
          az += (v0.z+v1.z)+(v2.z+v3.z);
          aw += (v0.w+v1.w)+(v2.w+v3.w);
        }
        for (; k<e; ++k){
          float4 v = X4[(size_t)colAt(k)*32+c];
          ax+=v.x; ay+=v.y; az+=v.z; aw+=v.w;
        }
        float invd = 1.0f / (float)((e>b)?(e-b):1u);
        *(float4*)&smemA[n][4*c] = make_float4(ax*invd, ay*invd, az*invd, aw*invd);
      }
    };
    if (ecnt <= EMAX) gather([&](uint32_t k){ return lcol[k]; });
    else              gather([&](uint32_t k){ return col[e0+k]; });
  }
  __syncthreads();

  // ---- phase 2: MFMA ----
  const int l = t & 63, wid = t >> 6;
  const int q = l >> 4, c16 = l & 15;
  const int arow = rowBase + wid*16 + c16;

  f32x4 acc[8];
  #pragma unroll
  for (int ct=0; ct<8; ++ct) acc[ct] = (f32x4){0.f,0.f,0.f,0.f};

  #pragma unroll
  for (int ks=0; ks<8; ++ks){
    float4 A0, A1;
    if (ks < 4){
      const float* s = &smemA[wid*16 + c16][ks*32 + q*8];
      A0 = *(const float4*)s; A1 = *(const float4*)(s+4);
    } else {
      const float* s = Xin + (size_t)arow*DF + (ks-4)*32 + q*8;
      A0 = *(const float4*)s; A1 = *(const float4*)(s+4);
    }
    float v[8] = {A0.x,A0.y,A0.z,A0.w,A1.x,A1.y,A1.z,A1.w};
    bf16x8 ahi, alo;
    #pragma unroll
    for (int j=0;j<8;++j){
      unsigned short h, lo_; split2(v[j], h, lo_);
      ahi[j] = (short)h; alo[j] = (short)lo_;
    }
    const unsigned short* bp = Bpk + (size_t)ks*8192 + l*8;
    #pragma unroll
    for (int ct=0; ct<8; ++ct){
      bf16x8 bhi = *(const bf16x8*)(bp + ct*1024);
      bf16x8 blo = *(const bf16x8*)(bp + ct*1024 + 512);
      acc[ct] = __builtin_amdgcn_mfma_f32_16x16x32_bf16(ahi, bhi, acc[ct], 0,0,0);
      acc[ct] = __builtin_amdgcn_mfma_f32_16x16x32_bf16(ahi, blo, acc[ct], 0,0,0);
      acc[ct] = __builtin_amdgcn_mfma_f32_16x16x32_bf16(alo, bhi, acc[ct], 0,0,0);
    }
  }

  // ---- epilogue ----
  const int rowOut = rowBase + wid*16;
  if constexpr (LAYER==1){
    #pragma unroll
    for (int ct=0; ct<8; ++ct){
      int c = ct*16 + c16;
      float bv = bias[c];
      #pragma unroll
      for (int r=0; r<4; ++r){
        int grow = rowOut + q*4 + r;
        OUT[(size_t)grow*DF + c] = fmaxf(acc[ct][r] + bv, 0.f);
      }
    }
  } else {
    float ov[8][4];
    float pwv[8];
    float n2 = 0.f;
    #pragma unroll
    for (int ct=0; ct<8; ++ct){ pwv[ct] = pw[ct*16 + c16]; n2 += pwv[ct]*pwv[ct]; }
    n2 += __shfl_xor(n2,8,16); n2 += __shfl_xor(n2,4,16);
    n2 += __shfl_xor(n2,2,16); n2 += __shfl_xor(n2,1,16);
    float nrm = sqrtf(n2);
    #pragma unroll
    for (int ct=0; ct<8; ++ct){
      int c = ct*16 + c16;
      float bv = bias[c];
      #pragma unroll
      for (int r=0; r<4; ++r){
        int grow = rowOut + q*4 + r;
        float o = fmaxf(acc[ct][r] + bv, 0.f);
        OUT[(size_t)grow*DF + c] = o;
        ov[ct][r] = o;
      }
    }
    #pragma unroll
    for (int r=0; r<4; ++r){
      float p = 0.f;
      #pragma unroll
      for (int ct=0; ct<8; ++ct) p += ov[ct][r]*pwv[ct];
      p += __shfl_xor(p,8,16); p += __shfl_xor(p,4,16);
      p += __shfl_xor(p,2,16); p += __shfl_xor(p,1,16);
      if (c16 == 0) scores[rowOut + q*4 + r] = tanhf(p/nrm);
    }
  }
}

// ---------------- top-k via radix-select + pool + classifier ---------------
__global__ __launch_bounds__(1024) void k_topk(
    const float* __restrict__ scores, const float* __restrict__ H,
    const float* __restrict__ Wc1, const float* __restrict__ bc1,
    const float* __restrict__ Wc2, const float* __restrict__ bc2,
    float* __restrict__ out)
{
  __shared__ uint32_t keys[NNODE];            // 8KB monotone keys
  __shared__ uint32_t hist[64];
  __shared__ uint32_t wsum[16];               // block-scan wave sums
  __shared__ uint32_t sh_b, sh_rank, sh_cnt;
  __shared__ unsigned short selidx[KSEL+1];
  __shared__ float selval[KSEL+1];
  __shared__ float part[8*DF];
  __shared__ float emb[DF];
  __shared__ float hred[DF];

  const int t = threadIdx.x; const int b = blockIdx.x;
  const int lane = t & 63, wid = t >> 6;
  const float* sc = scores + b*NNODE;

  for (int i=t; i<NNODE; i+=1024) keys[i] = f2mono(sc[i]);
  __syncthreads();

  // ---- radix select: find threshold key T = 615th largest ----
  uint32_t prefix = 0, prefmask = 0, rank = KSEL, cntT = 0;
  #pragma unroll
  for (int lev=0; lev<6; ++lev){
    const int shift = (lev<5) ? (26 - 6*lev) : 0;
    const uint32_t bmask = (lev<5) ? 63u : 3u;
    if (t < 64) hist[t] = 0;
    __syncthreads();
    for (int i=t; i<NNODE; i+=1024){
      uint32_t k = keys[i];
      if ((k & prefmask) == prefix) atomicAdd(&hist[(k>>shift)&bmask], 1u);
    }
    __syncthreads();
    if (t < 64){
      uint32_t x = hist[t];
      #pragma unroll
      for (int off=1; off<64; off<<=1){        // inclusive suffix sum
        uint32_t y = __shfl_down(x, off, 64);
        if (t + off < 64) x += y;
      }
      uint32_t above = __shfl_down(x, 1, 64);
      if (t == 63) above = 0;
      if (above < rank && rank <= x){
        sh_b = (uint32_t)t; sh_rank = rank - above; sh_cnt = x - above;
      }
    }
    __syncthreads();
    prefix |= (sh_b << shift);
    prefmask |= (bmask << shift);
    rank = sh_rank; cntT = sh_cnt;
    __syncthreads();
  }
  const uint32_t T = prefix;
  const uint32_t m = rank;

  // ---- selection + compaction (block scans, shfl-based) ----
  uint32_t k0 = keys[2*t], k1 = keys[2*t+1];
  uint32_t eq0 = (k0 == T), eq1 = (k1 == T);
  uint32_t eqr0 = 0, eqr1 = 0;

  if (m != cntT){
    uint32_t v = eq0 + eq1, x = v;
    #pragma unroll
    for (int off=1; off<64; off<<=1){
      uint32_t y = __shfl_up(x, off, 64);
      if (lane >= off) x += y;
    }
    if (lane == 63) wsum[wid] = x;
    __syncthreads();
    if (wid == 0){
      uint32_t s = (lane < 16) ? wsum[lane] : 0;
      #pragma unroll
      for (int off=1; off<16; off<<=1){
        uint32_t y = __shfl_up(s, off, 64);
        if (lane >= off) s += y;
      }
      if (lane < 16) wsum[lane] = s;
    }
    __syncthreads();
    uint32_t excl = (wid ? wsum[wid-1] : 0) + x - v;
    eqr0 = excl; eqr1 = excl + eq0;
    __syncthreads();
  }

  uint32_t sel0 = (k0 > T) || (eq0 && eqr0 < m);
  uint32_t sel1 = (k1 > T) || (eq1 && eqr1 < m);
  {
    uint32_t v = sel0 + sel1, x = v;
    #pragma unroll
    for (int off=1; off<64; off<<=1){
      uint32_t y = __shfl_up(x, off, 64);
      if (lane >= off) x += y;
    }
    if (lane == 63) wsum[wid] = x;
    __syncthreads();
    if (wid == 0){
      uint32_t s = (lane < 16) ? wsum[lane] : 0;
      #pragma unroll
      for (int off=1; off<16; off<<=1){
        uint32_t y = __shfl_up(s, off, 64);
        if (lane >= off) s += y;
      }
      if (lane < 16) wsum[lane] = s;
    }
    __syncthreads();
    uint32_t excl = (wid ? wsum[wid-1] : 0) + x - v;
    if (sel0){ selidx[excl] = (unsigned short)(2*t);   selval[excl] = mono2f(k0); }
    if (sel1){ selidx[excl+sel0] = (unsigned short)(2*t+1); selval[excl+sel0] = mono2f(k1); }
  }
  __syncthreads();

  // ---- gated mean over the 615 selected rows (4-deep unrolled gather) ----
  const int pg = t >> 7, f = t & (DF-1);
  const float* Hb = H + (size_t)b*NNODE*DF;
  float accv = 0.f;
  int s2 = pg;
  for (; s2+24 < KSEL; s2 += 32){
    int i0=selidx[s2], i1=selidx[s2+8], i2=selidx[s2+16], i3=selidx[s2+24];
    float w0=selval[s2], w1=selval[s2+8], w2=selval[s2+16], w3=selval[s2+24];
    float v0=Hb[(size_t)i0*DF+f], v1=Hb[(size_t)i1*DF+f],
          v2=Hb[(size_t)i2*DF+f], v3=Hb[(size_t)i3*DF+f];
    accv += w0*v0 + w1*v1 + w2*v2 + w3*v3;
  }
  for (; s2<KSEL; s2+=8) accv += selval[s2]*Hb[(size_t)selidx[s2]*DF+f];
  part[pg*DF + f] = accv;
  __syncthreads();
  if (t < DF){
    float e = 0.f;
    for (int g2=0; g2<8; ++g2) e += part[g2*DF + t];
    emb[t] = e / (float)KSEL;
  }
  __syncthreads();
  if (t < DF){
    float hv = bc1[t];
    const float* wr = Wc1 + t*DF;
    for (int f2=0; f2<DF; ++f2) hv = fmaf(emb[f2], wr[f2], hv);
    hred[t] = fmaxf(hv, 0.f) * Wc2[t];
  }
  __syncthreads();
  if (t == 0){
    float o = bc2[0];
    for (int c2=0; c2<DF; ++c2) o += hred[c2];
    out[b] = o;
  }
}

// ---------------- launch ----------------
extern "C" void kernel_launch(void* const* d_in, const int* in_sizes, int n_in,
                              void* d_out, int out_size, void* d_ws, size_t ws_size,
                              hipStream_t stream)
{
  (void)in_sizes; (void)n_in; (void)out_size; (void)ws_size;
  const float* x   = (const float*)d_in[0];
  const int* esrc  = (const int*)d_in[1];
  const int* edst  = (const int*)d_in[2];
  const float* Wl1 = (const float*)d_in[3];
  const float* bl1 = (const float*)d_in[4];
  const float* Wr1 = (const float*)d_in[5];
  const float* Wl2 = (const float*)d_in[6];
  const float* bl2 = (const float*)d_in[7];
  const float* Wr2 = (const float*)d_in[8];
  const float* pw  = (const float*)d_in[9];
  const float* Wc1 = (const float*)d_in[10];
  const float* bc1 = (const float*)d_in[11];
  const float* Wc2 = (const float*)d_in[12];
  const float* bc2 = (const float*)d_in[13];
  float* out = (float*)d_out;

  char* ws = (char*)d_ws;                       // ~70.3 MB used
  float*    H1     = (float*)   (ws + 0);          // 32MB
  float*    H2     = (float*)   (ws + 33554432);   // 32MB
  uint32_t* deg    = (uint32_t*)(ws + 67108864);   // 256KB
  uint32_t* rowptr = (uint32_t*)(ws + 67371008);   // 65537 u32
  int*      col    = (int*)     (ws + 67633408);   // 2MB
  float*    scores = (float*)   (ws + 69730560);   // 256KB
  uint32_t* bsum   = (uint32_t*)(ws + 69992704);   // 256B
  unsigned short* Bpk = (unsigned short*)(ws + 69992960); // 256KB (2 layers)

  hipMemsetAsync(deg, 0, NT*sizeof(uint32_t), stream);

  k_deg    <<<ETOT/256, 256, 0, stream>>>(edst, deg);
  k_scan1  <<<64, 1024, 0, stream>>>(deg, rowptr, bsum);
  k_scan2  <<<1, 64, 0, stream>>>(bsum);
  k_scan3  <<<64, 1024, 0, stream>>>(rowptr, bsum);
  k_scatter<<<ETOT/256, 256, 0, stream>>>(esrc, edst, rowptr, deg, col);

  k_packB<<<16, 256, 0, stream>>>(Wl1, Wr1, Bpk);
  k_packB<<<16, 256, 0, stream>>>(Wl2, Wr2, Bpk + 65536);

  // fused layers: gather+mean+GEMM per block
  k_sage<1><<<NT/32, 128, 0, stream>>>(x,  rowptr, col, Bpk,         bl1,
                                       H1, nullptr, nullptr);
  k_sage<2><<<NT/32, 128, 0, stream>>>(H1, rowptr, col, Bpk + 65536, bl2,
                                       H2, pw, scores);

  k_topk<<<NB, 1024, 0, stream>>>(scores, H2, Wc1, bc1, Wc2, bc2, out);
}